// Round 1
// baseline (2785.129 us; speedup 1.0000x reference)
//
#include <hip/hip_runtime.h>
#include <hip/hip_bf16.h>

#define HID 256
#define NGRAPH 2048

// ---------------- Atom encoder ----------------
__global__ __launch_bounds__(256) void atom_enc(const int* __restrict__ x,
                                                const float* __restrict__ emb,
                                                float* __restrict__ h, int N) {
    int n = blockIdx.x;
    int c = threadIdx.x;
    if (n >= N) return;
    const int offs[9] = {0, 119, 124, 136, 148, 158, 164, 170, 172};
    float s = 0.f;
#pragma unroll
    for (int j = 0; j < 9; ++j) {
        int row = x[n * 9 + j] + offs[j];
        s += emb[row * 256 + c];
    }
    h[n * 256 + c] = s;
}

// ---------------- CSR build ----------------
__global__ void init_cnt(int* cnt, int N) {
    int i = blockIdx.x * blockDim.x + threadIdx.x;
    if (i < N) cnt[i] = 1;  // self loop
}

__global__ void csr_count(const int* __restrict__ ei, int E, int* cnt) {
    int e = blockIdx.x * blockDim.x + threadIdx.x;
    if (e >= E) return;
    atomicAdd(&cnt[ei[e]], 1);
}

__global__ __launch_bounds__(1024) void scan_kernel(const int* __restrict__ cnt,
                                                    int* __restrict__ row_ptr, int N) {
    __shared__ int buf[1024];
    __shared__ int carry;
    if (threadIdx.x == 0) carry = 0;
    __syncthreads();
    for (int base = 0; base < N; base += 1024) {
        int i = base + threadIdx.x;
        int v = (i < N) ? cnt[i] : 0;
        buf[threadIdx.x] = v;
        __syncthreads();
        for (int off = 1; off < 1024; off <<= 1) {
            int t = (threadIdx.x >= off) ? buf[threadIdx.x - off] : 0;
            __syncthreads();
            buf[threadIdx.x] += t;
            __syncthreads();
        }
        int incl = buf[threadIdx.x];
        int excl = incl - v;
        int c = carry;
        if (i < N) row_ptr[i] = c + excl;
        int total = buf[1023];
        __syncthreads();
        if (threadIdx.x == 0) carry = c + total;
        __syncthreads();
    }
    if (threadIdx.x == 0) row_ptr[N] = carry;
}

__global__ void copy_woff(const int* __restrict__ row_ptr, int* __restrict__ woff, int N) {
    int i = blockIdx.x * blockDim.x + threadIdx.x;
    if (i < N) woff[i] = row_ptr[i];
}

__global__ void csr_scatter(const int* __restrict__ ei, int E, int N,
                            int* __restrict__ woff, int* __restrict__ srcs) {
    int i = blockIdx.x * blockDim.x + threadIdx.x;
    if (i >= E + N) return;
    int d, s;
    if (i < E) { d = ei[i]; s = ei[E + i]; }
    else       { d = i - E; s = i - E; }
    int pos = atomicAdd(&woff[d], 1);
    srcs[pos] = s;
}

// ---------------- Per-layer fused GEMM: bases (128) + wts (96) ----------------
// h [N,256] @ Wb [256,128] -> bases; h @ Wc [256,96] + cb -> wts
__global__ __launch_bounds__(256) void gemm_layer(const float* __restrict__ h,
                                                  const float* __restrict__ Wb,
                                                  const float* __restrict__ Wc,
                                                  const float* __restrict__ cb,
                                                  float* __restrict__ bases,
                                                  float* __restrict__ wts, int N) {
    __shared__ float hT[16][64];
    __shared__ float ws[16][224];
    int r0 = blockIdx.x * 64;
    int tid = threadIdx.x;
    int tn = tid >> 5;   // 0..7
    int tc = tid & 31;   // 0..31
    float acc[8][7];
#pragma unroll
    for (int i = 0; i < 8; ++i)
#pragma unroll
        for (int j = 0; j < 7; ++j) acc[i][j] = 0.f;

    for (int k0 = 0; k0 < 256; k0 += 16) {
        {
            int m = tid >> 2;
            int kk = (tid & 3) * 4;
            int row = r0 + m;
            float4 v = make_float4(0.f, 0.f, 0.f, 0.f);
            if (row < N) v = *(const float4*)&h[row * 256 + k0 + kk];
            hT[kk + 0][m] = v.x;
            hT[kk + 1][m] = v.y;
            hT[kk + 2][m] = v.z;
            hT[kk + 3][m] = v.w;
        }
#pragma unroll
        for (int t = 0; t < 14; ++t) {
            int idx = tid + 256 * t;
            int kk = idx / 224;
            int j = idx - kk * 224;
            float w = (j < 128) ? Wb[(k0 + kk) * 128 + j] : Wc[(k0 + kk) * 96 + (j - 128)];
            ws[kk][j] = w;
        }
        __syncthreads();
#pragma unroll
        for (int kk = 0; kk < 16; ++kk) {
            float a[8], b[7];
#pragma unroll
            for (int i = 0; i < 8; ++i) a[i] = hT[kk][tn + 8 * i];
#pragma unroll
            for (int j = 0; j < 7; ++j) b[j] = ws[kk][tc + 32 * j];
#pragma unroll
            for (int i = 0; i < 8; ++i)
#pragma unroll
                for (int j = 0; j < 7; ++j) acc[i][j] = fmaf(a[i], b[j], acc[i][j]);
        }
        __syncthreads();
    }
#pragma unroll
    for (int i = 0; i < 8; ++i) {
        int row = r0 + tn + 8 * i;
        if (row >= N) continue;
#pragma unroll
        for (int j = 0; j < 7; ++j) {
            int col = tc + 32 * j;
            if (col < 128) bases[row * 128 + col] = acc[i][j];
            else wts[row * 96 + (col - 128)] = acc[i][j] + cb[col - 128];
        }
    }
}

// ---------------- Aggregation (sum/mean/max) + einsum + conv_bias ----------------
// one wave per node; block = 4 waves
__global__ __launch_bounds__(256) void agg_einsum(const float* __restrict__ bases,
                                                  const float* __restrict__ wts,
                                                  const int* __restrict__ row_ptr,
                                                  const int* __restrict__ srcs,
                                                  const float* __restrict__ cbias,
                                                  float* __restrict__ outp, int N) {
    __shared__ float agg_lds[4][3][128];
    __shared__ float wts_lds[4][96];
    int wid = threadIdx.x >> 6;
    int lane = threadIdx.x & 63;
    int n = blockIdx.x * 4 + wid;
    bool valid = (n < N);
    if (valid) {
        int r0 = row_ptr[n];
        int r1 = row_ptr[n + 1];
        float sx = 0.f, sy = 0.f;
        float mx = -3.402823466e+38f, my = -3.402823466e+38f;
        for (int r = r0; r < r1; ++r) {
            int s = srcs[r];
            float2 v = *(const float2*)&bases[s * 128 + 2 * lane];
            sx += v.x; sy += v.y;
            mx = fmaxf(mx, v.x); my = fmaxf(my, v.y);
        }
        float inv = 1.0f / (float)(r1 - r0);
        agg_lds[wid][0][2 * lane] = sx;      agg_lds[wid][0][2 * lane + 1] = sy;
        agg_lds[wid][1][2 * lane] = sx * inv; agg_lds[wid][1][2 * lane + 1] = sy * inv;
        agg_lds[wid][2][2 * lane] = mx;      agg_lds[wid][2][2 * lane + 1] = my;
        wts_lds[wid][lane] = (lane < 96) ? 0.f : 0.f;  // placeholder, overwritten below
        wts_lds[wid][lane] = wts[n * 96 + lane] * 0.f; // avoid OOB? lane<64 ok
        wts_lds[wid][lane] = wts[n * 96 + lane];       // lane 0..63
        if (lane < 32) wts_lds[wid][64 + lane] = wts[n * 96 + 64 + lane];
    }
    __syncthreads();
    if (valid) {
#pragma unroll
        for (int j = 0; j < 4; ++j) {
            int o = lane + 64 * j;
            int hh = o >> 5;
            int d = o & 31;
            float acc = cbias[o];
#pragma unroll
            for (int k = 0; k < 12; ++k)
                acc = fmaf(wts_lds[wid][hh * 12 + k], agg_lds[wid][k >> 2][(k & 3) * 32 + d], acc);
            outp[n * 256 + o] = acc;
        }
    }
}

// ---------------- BN (2-stage, deterministic) ----------------
__global__ void bn_stats(const float* __restrict__ v, int N, int C, float* __restrict__ partial) {
    int c = threadIdx.x;  // blockDim == C
    float s = 0.f, s2 = 0.f;
    for (int r = blockIdx.x; r < N; r += gridDim.x) {
        float t = v[r * C + c];
        s += t; s2 += t * t;
    }
    partial[(blockIdx.x * 2 + 0) * C + c] = s;
    partial[(blockIdx.x * 2 + 1) * C + c] = s2;
}

__global__ void bn_finalize(const float* __restrict__ partial, int NB, int C, int N,
                            const float* __restrict__ gamma, const float* __restrict__ beta,
                            float* __restrict__ ss) {
    int c = threadIdx.x;
    if (c >= C) return;
    float s = 0.f, s2 = 0.f;
    for (int b = 0; b < NB; ++b) {
        s += partial[(b * 2 + 0) * C + c];
        s2 += partial[(b * 2 + 1) * C + c];
    }
    float invN = 1.0f / (float)N;
    float mu = s * invN;
    float var = fmaxf(s2 * invN - mu * mu, 0.f);
    float sc = gamma[c] * rsqrtf(var + 1e-5f);
    ss[c] = sc;
    ss[C + c] = beta[c] - mu * sc;
}

// h += relu(out*sc+sh), C=256, vectorized x4
__global__ void bn_apply_res4(float4* __restrict__ h, const float4* __restrict__ outp,
                              const float* __restrict__ ss, int total4) {
    int i = blockIdx.x * blockDim.x + threadIdx.x;
    if (i >= total4) return;
    int c0 = (i * 4) & 255;
    float4 o = outp[i];
    float4 hv = h[i];
    hv.x += fmaxf(o.x * ss[c0 + 0] + ss[256 + c0 + 0], 0.f);
    hv.y += fmaxf(o.y * ss[c0 + 1] + ss[256 + c0 + 1], 0.f);
    hv.z += fmaxf(o.z * ss[c0 + 2] + ss[256 + c0 + 2], 0.f);
    hv.w += fmaxf(o.w * ss[c0 + 3] + ss[256 + c0 + 3], 0.f);
    h[i] = hv;
}

// z = relu(z*sc+sh), in place, C power of 2
__global__ void bn_apply(float* __restrict__ z, const float* __restrict__ ss, int total, int C, int Cmask) {
    int i = blockIdx.x * blockDim.x + threadIdx.x;
    if (i >= total) return;
    int c = i & Cmask;
    z[i] = fmaxf(z[i] * ss[c] + ss[C + c], 0.f);
}

// ---------------- Pool ----------------
__device__ int lower_bound_dev(const int* a, int n, int v) {
    int lo = 0, hi = n;
    while (lo < hi) {
        int mid = (lo + hi) >> 1;
        if (a[mid] < v) lo = mid + 1; else hi = mid;
    }
    return lo;
}

__global__ __launch_bounds__(256) void pool_kernel(const float* __restrict__ h,
                                                   const int* __restrict__ batch, int N,
                                                   float* __restrict__ g) {
    __shared__ int sh[2];
    if (threadIdx.x == 0) {
        sh[0] = lower_bound_dev(batch, N, (int)blockIdx.x);
        sh[1] = lower_bound_dev(batch, N, (int)blockIdx.x + 1);
    }
    __syncthreads();
    int s0 = sh[0], s1 = sh[1];
    float s = 0.f;
    for (int r = s0; r < s1; ++r) s += h[r * 256 + threadIdx.x];
    float cnt = (float)(s1 - s0);
    g[blockIdx.x * 256 + threadIdx.x] = s / fmaxf(cnt, 1.0f);
}

// ---------------- MLP ----------------
__global__ void mlp_gemm(const float* __restrict__ in, const float* __restrict__ W,
                         float* __restrict__ outp, int K, int C) {
    extern __shared__ float srow[];
    int r = blockIdx.x;
    for (int k = threadIdx.x; k < K; k += blockDim.x) srow[k] = in[r * K + k];
    __syncthreads();
    int c = threadIdx.x;
    float acc = 0.f;
    for (int k = 0; k < K; ++k) acc = fmaf(srow[k], W[k * C + c], acc);
    outp[r * C + c] = acc;
}

__global__ void final_gemm(const float* __restrict__ z2, const float* __restrict__ w3,
                           const float* __restrict__ b3, float* __restrict__ outp, int G) {
    int g = blockIdx.x * blockDim.x + threadIdx.x;
    if (g >= G) return;
    float acc = b3[0];
    for (int k = 0; k < 64; ++k) acc = fmaf(z2[g * 64 + k], w3[k], acc);
    outp[g] = acc;
}

extern "C" void kernel_launch(void* const* d_in, const int* in_sizes, int n_in,
                              void* d_out, int out_size, void* d_ws, size_t ws_size,
                              hipStream_t stream) {
    const float* atom_emb = (const float*)d_in[0];
    const float* bases_W = (const float*)d_in[1];
    const float* comb_W = (const float*)d_in[2];
    const float* comb_b = (const float*)d_in[3];
    const float* conv_bias = (const float*)d_in[4];
    const float* bn_gamma = (const float*)d_in[5];
    const float* bn_beta = (const float*)d_in[6];
    const float* w1 = (const float*)d_in[7];
    const float* g1 = (const float*)d_in[8];
    const float* b1 = (const float*)d_in[9];
    const float* w2 = (const float*)d_in[10];
    const float* g2 = (const float*)d_in[11];
    const float* b2 = (const float*)d_in[12];
    const float* w3 = (const float*)d_in[13];
    const float* b3 = (const float*)d_in[14];
    const int* x = (const int*)d_in[15];
    const int* edge_index = (const int*)d_in[16];
    const int* batch = (const int*)d_in[17];
    float* out = (float*)d_out;

    const int N = in_sizes[15] / 9;
    const int E = in_sizes[16] / 2;
    const int G = NGRAPH;

    // workspace carve
    char* p = (char*)d_ws;
    auto alloc = [&](size_t bytes) -> void* {
        void* r = (void*)p;
        p += (bytes + 255) & ~(size_t)255;
        return r;
    };
    float* h = (float*)alloc((size_t)N * 256 * 4);
    float* outb = (float*)alloc((size_t)N * 256 * 4);
    float* bases = (float*)alloc((size_t)N * 128 * 4);
    float* wts = (float*)alloc((size_t)N * 96 * 4);
    int* row_ptr = (int*)alloc((size_t)(N + 1) * 4);
    int* cnt = (int*)alloc((size_t)N * 4);  // reused as woff
    int* srcs = (int*)alloc((size_t)(E + N) * 4);
    float* partial = (float*)alloc((size_t)256 * 2 * 256 * 4);
    float* ss = (float*)alloc((size_t)2 * 256 * 4);
    float* g = (float*)alloc((size_t)G * 256 * 4);
    float* z1 = (float*)alloc((size_t)G * 128 * 4);
    float* z2 = (float*)alloc((size_t)G * 64 * 4);

    // atom encoder
    atom_enc<<<N, 256, 0, stream>>>(x, atom_emb, h, N);

    // CSR build
    init_cnt<<<(N + 255) / 256, 256, 0, stream>>>(cnt, N);
    csr_count<<<(E + 255) / 256, 256, 0, stream>>>(edge_index, E, cnt);
    scan_kernel<<<1, 1024, 0, stream>>>(cnt, row_ptr, N);
    copy_woff<<<(N + 255) / 256, 256, 0, stream>>>(row_ptr, cnt, N);
    csr_scatter<<<(E + N + 255) / 256, 256, 0, stream>>>(edge_index, E, N, cnt, srcs);

    const int NB = 240;
    for (int l = 0; l < 4; ++l) {
        const float* Wb = bases_W + (size_t)l * 256 * 128;
        const float* Wc = comb_W + (size_t)l * 256 * 96;
        const float* cb = comb_b + (size_t)l * 96;
        const float* cbias = conv_bias + (size_t)l * 256;
        const float* gam = bn_gamma + (size_t)l * 256;
        const float* bet = bn_beta + (size_t)l * 256;

        gemm_layer<<<(N + 63) / 64, 256, 0, stream>>>(h, Wb, Wc, cb, bases, wts, N);
        agg_einsum<<<(N + 3) / 4, 256, 0, stream>>>(bases, wts, row_ptr, srcs, cbias, outb, N);
        bn_stats<<<NB, 256, 0, stream>>>(outb, N, 256, partial);
        bn_finalize<<<1, 256, 0, stream>>>(partial, NB, 256, N, gam, bet, ss);
        int total4 = N * 256 / 4;
        bn_apply_res4<<<(total4 + 255) / 256, 256, 0, stream>>>((float4*)h, (const float4*)outb, ss, total4);
    }

    // pool
    pool_kernel<<<G, 256, 0, stream>>>(h, batch, N, g);

    // MLP layer 1: 256 -> 128
    mlp_gemm<<<G, 128, 256 * 4, stream>>>(g, w1, z1, 256, 128);
    bn_stats<<<64, 128, 0, stream>>>(z1, G, 128, partial);
    bn_finalize<<<1, 128, 0, stream>>>(partial, 64, 128, G, g1, b1, ss);
    bn_apply<<<(G * 128 + 255) / 256, 256, 0, stream>>>(z1, ss, G * 128, 128, 127);

    // MLP layer 2: 128 -> 64
    mlp_gemm<<<G, 64, 128 * 4, stream>>>(z1, w2, z2, 128, 64);
    bn_stats<<<64, 64, 0, stream>>>(z2, G, 64, partial);
    bn_finalize<<<1, 64, 0, stream>>>(partial, 64, 64, G, g2, b2, ss);
    bn_apply<<<(G * 64 + 255) / 256, 256, 0, stream>>>(z2, ss, G * 64, 64, 63);

    // final: 64 -> 1
    final_gemm<<<(G + 255) / 256, 256, 0, stream>>>(z2, w3, b3, out, G);
}

// Round 2
// 1625.415 us; speedup vs baseline: 1.7135x; 1.7135x over previous
//
#include <hip/hip_runtime.h>
#include <hip/hip_bf16.h>

#define HID 256
#define NGRAPH 2048

typedef __attribute__((ext_vector_type(8))) short s16x8;
typedef __attribute__((ext_vector_type(4))) float f32x4v;

__device__ inline short f2b(float f) {
    __hip_bfloat16 b = __float2bfloat16(f);
    return *reinterpret_cast<short*>(&b);
}
__device__ inline float b2f_lo(unsigned int v) {
    return __uint_as_float(v << 16);
}
__device__ inline float b2f_hi(unsigned int v) {
    return __uint_as_float(v & 0xffff0000u);
}

// ---------------- Atom encoder: h fp32 + bf16 mirror ----------------
__global__ __launch_bounds__(256) void atom_enc(const int* __restrict__ x,
                                                const float* __restrict__ emb,
                                                float* __restrict__ h,
                                                short* __restrict__ hb, int N) {
    int n = blockIdx.x;
    int c = threadIdx.x;
    if (n >= N) return;
    const int offs[9] = {0, 119, 124, 136, 148, 158, 164, 170, 172};
    float s = 0.f;
#pragma unroll
    for (int j = 0; j < 9; ++j) {
        int row = x[n * 9 + j] + offs[j];
        s += emb[row * 256 + c];
    }
    h[n * 256 + c] = s;
    hb[n * 256 + c] = f2b(s);
}

// ---------------- Weight prep: combined [224][256] bf16 transposed, per layer ----------------
__global__ void prep_wt(const float* __restrict__ bases_W, const float* __restrict__ comb_W,
                        short* __restrict__ WT) {
    int l = blockIdx.x / 224;
    int n = blockIdx.x % 224;
    int k = threadIdx.x;  // 0..255
    float v = (n < 128) ? bases_W[((size_t)l * 256 + k) * 128 + n]
                        : comb_W[((size_t)l * 256 + k) * 96 + (n - 128)];
    WT[((size_t)l * 224 + n) * 256 + k] = f2b(v);
}

// ---------------- CSR build ----------------
__global__ void init_cnt(int* cnt, int N) {
    int i = blockIdx.x * blockDim.x + threadIdx.x;
    if (i < N) cnt[i] = 1;  // self loop
}

__global__ void csr_count(const int* __restrict__ ei, int E, int* cnt) {
    int e = blockIdx.x * blockDim.x + threadIdx.x;
    if (e >= E) return;
    atomicAdd(&cnt[ei[e]], 1);
}

__global__ __launch_bounds__(1024) void scan_kernel(const int* __restrict__ cnt,
                                                    int* __restrict__ row_ptr, int N) {
    __shared__ int buf[1024];
    __shared__ int carry;
    if (threadIdx.x == 0) carry = 0;
    __syncthreads();
    for (int base = 0; base < N; base += 1024) {
        int i = base + threadIdx.x;
        int v = (i < N) ? cnt[i] : 0;
        buf[threadIdx.x] = v;
        __syncthreads();
        for (int off = 1; off < 1024; off <<= 1) {
            int t = (threadIdx.x >= off) ? buf[threadIdx.x - off] : 0;
            __syncthreads();
            buf[threadIdx.x] += t;
            __syncthreads();
        }
        int incl = buf[threadIdx.x];
        int excl = incl - v;
        int c = carry;
        if (i < N) row_ptr[i] = c + excl;
        int total = buf[1023];
        __syncthreads();
        if (threadIdx.x == 0) carry = c + total;
        __syncthreads();
    }
    if (threadIdx.x == 0) row_ptr[N] = carry;
}

__global__ void copy_woff(const int* __restrict__ row_ptr, int* __restrict__ woff, int N) {
    int i = blockIdx.x * blockDim.x + threadIdx.x;
    if (i < N) woff[i] = row_ptr[i];
}

__global__ void csr_scatter(const int* __restrict__ ei, int E, int N,
                            int* __restrict__ woff, int* __restrict__ srcs) {
    int i = blockIdx.x * blockDim.x + threadIdx.x;
    if (i >= E + N) return;
    int d, s;
    if (i < E) { d = ei[i]; s = ei[E + i]; }
    else       { d = i - E; s = i - E; }
    int pos = atomicAdd(&woff[d], 1);
    srcs[pos] = s;
}

// ---------------- MFMA GEMM: hb[N,256] @ WT^T -> bases bf16 [N,128], wts fp32 [N,96] ----------------
// 4 waves/block; each wave: 16 rows x 224 cols, 14 acc tiles of 16x16x32 bf16.
__global__ __launch_bounds__(256) void gemm_mfma(const short* __restrict__ hb,
                                                 const short* __restrict__ WT,
                                                 const float* __restrict__ cb,
                                                 short* __restrict__ bases,
                                                 float* __restrict__ wts, int N) {
    int wid = threadIdx.x >> 6;
    int lane = threadIdx.x & 63;
    int m0 = blockIdx.x * 64 + wid * 16;
    int row_a = m0 + (lane & 15);
    if (row_a > N - 1) row_a = N - 1;
    int kgrp = (lane >> 4) * 8;  // 0,8,16,24 within each K=32 step

    // load whole K=256 strip of A for this row: 8 frags x 8 bf16
    s16x8 a[8];
#pragma unroll
    for (int i = 0; i < 8; ++i)
        a[i] = *(const s16x8*)&hb[(size_t)row_a * 256 + i * 32 + kgrp];

    f32x4v acc[14];
#pragma unroll 2
    for (int t = 0; t < 14; ++t) {
        const short* bp = &WT[(size_t)(t * 16 + (lane & 15)) * 256 + kgrp];
        f32x4v c = {0.f, 0.f, 0.f, 0.f};
#pragma unroll
        for (int i = 0; i < 8; ++i) {
            s16x8 b = *(const s16x8*)&bp[i * 32];
            c = __builtin_amdgcn_mfma_f32_16x16x32_bf16(a[i], b, c, 0, 0, 0);
        }
        acc[t] = c;
    }

    // epilogue: D[row=(lane>>4)*4+r][col=lane&15]
    int rbase = m0 + (lane >> 4) * 4;
    int col = lane & 15;
#pragma unroll
    for (int t = 0; t < 14; ++t) {
        int n0 = t * 16;
#pragma unroll
        for (int r = 0; r < 4; ++r) {
            int row = rbase + r;
            if (row >= N) continue;
            float v = acc[t][r];
            int cc = n0 + col;
            if (cc < 128) bases[(size_t)row * 128 + cc] = f2b(v);
            else wts[(size_t)row * 96 + (cc - 128)] = v + cb[cc - 128];
        }
    }
}

// ---------------- Aggregation (sum/mean/max) + einsum + conv_bias ----------------
// one wave per node; block = 4 waves; bases is bf16 (2 cols/lane)
__global__ __launch_bounds__(256) void agg_einsum(const short* __restrict__ bases,
                                                  const float* __restrict__ wts,
                                                  const int* __restrict__ row_ptr,
                                                  const int* __restrict__ srcs,
                                                  const float* __restrict__ cbias,
                                                  float* __restrict__ outp, int N) {
    __shared__ float agg_lds[4][3][128];
    __shared__ float wts_lds[4][96];
    int wid = threadIdx.x >> 6;
    int lane = threadIdx.x & 63;
    int n = blockIdx.x * 4 + wid;
    bool valid = (n < N);
    if (valid) {
        int r0 = row_ptr[n];
        int r1 = row_ptr[n + 1];
        float sx = 0.f, sy = 0.f;
        float mx = -3.402823466e+38f, my = -3.402823466e+38f;
        for (int r = r0; r < r1; ++r) {
            int s = srcs[r];
            unsigned int v = *(const unsigned int*)&bases[(size_t)s * 128 + 2 * lane];
            float fx = b2f_lo(v), fy = b2f_hi(v);
            sx += fx; sy += fy;
            mx = fmaxf(mx, fx); my = fmaxf(my, fy);
        }
        float inv = 1.0f / (float)(r1 - r0);
        agg_lds[wid][0][2 * lane] = sx;       agg_lds[wid][0][2 * lane + 1] = sy;
        agg_lds[wid][1][2 * lane] = sx * inv; agg_lds[wid][1][2 * lane + 1] = sy * inv;
        agg_lds[wid][2][2 * lane] = mx;       agg_lds[wid][2][2 * lane + 1] = my;
        wts_lds[wid][lane] = wts[(size_t)n * 96 + lane];
        if (lane < 32) wts_lds[wid][64 + lane] = wts[(size_t)n * 96 + 64 + lane];
    }
    __syncthreads();
    if (valid) {
#pragma unroll
        for (int j = 0; j < 4; ++j) {
            int o = lane + 64 * j;
            int hh = o >> 5;
            int d = o & 31;
            float acc = cbias[o];
#pragma unroll
            for (int k = 0; k < 12; ++k)
                acc = fmaf(wts_lds[wid][hh * 12 + k], agg_lds[wid][k >> 2][(k & 3) * 32 + d], acc);
            outp[n * 256 + o] = acc;
        }
    }
}

// ---------------- BN (2-stage, deterministic) ----------------
__global__ void bn_stats(const float* __restrict__ v, int N, int C, float* __restrict__ partial) {
    int c = threadIdx.x;  // blockDim == C
    float s = 0.f, s2 = 0.f;
    for (int r = blockIdx.x; r < N; r += gridDim.x) {
        float t = v[r * C + c];
        s += t; s2 += t * t;
    }
    partial[(blockIdx.x * 2 + 0) * C + c] = s;
    partial[(blockIdx.x * 2 + 1) * C + c] = s2;
}

__global__ void bn_finalize(const float* __restrict__ partial, int NB, int C, int N,
                            const float* __restrict__ gamma, const float* __restrict__ beta,
                            float* __restrict__ ss) {
    int c = threadIdx.x;
    if (c >= C) return;
    float s = 0.f, s2 = 0.f;
    for (int b = 0; b < NB; ++b) {
        s += partial[(b * 2 + 0) * C + c];
        s2 += partial[(b * 2 + 1) * C + c];
    }
    float invN = 1.0f / (float)N;
    float mu = s * invN;
    float var = fmaxf(s2 * invN - mu * mu, 0.f);
    float sc = gamma[c] * rsqrtf(var + 1e-5f);
    ss[c] = sc;
    ss[C + c] = beta[c] - mu * sc;
}

// h += relu(out*sc+sh), C=256, vectorized x4; also writes bf16 mirror of h
__global__ void bn_apply_res4(float4* __restrict__ h, const float4* __restrict__ outp,
                              const float* __restrict__ ss, short* __restrict__ hb, int total4) {
    int i = blockIdx.x * blockDim.x + threadIdx.x;
    if (i >= total4) return;
    int c0 = (i * 4) & 255;
    float4 o = outp[i];
    float4 hv = h[i];
    hv.x += fmaxf(o.x * ss[c0 + 0] + ss[256 + c0 + 0], 0.f);
    hv.y += fmaxf(o.y * ss[c0 + 1] + ss[256 + c0 + 1], 0.f);
    hv.z += fmaxf(o.z * ss[c0 + 2] + ss[256 + c0 + 2], 0.f);
    hv.w += fmaxf(o.w * ss[c0 + 3] + ss[256 + c0 + 3], 0.f);
    h[i] = hv;
    short4 hb4;
    hb4.x = f2b(hv.x); hb4.y = f2b(hv.y); hb4.z = f2b(hv.z); hb4.w = f2b(hv.w);
    *(short4*)&hb[(size_t)i * 4] = hb4;
}

// z = relu(z*sc+sh), in place, C power of 2
__global__ void bn_apply(float* __restrict__ z, const float* __restrict__ ss, int total, int C, int Cmask) {
    int i = blockIdx.x * blockDim.x + threadIdx.x;
    if (i >= total) return;
    int c = i & Cmask;
    z[i] = fmaxf(z[i] * ss[c] + ss[C + c], 0.f);
}

// ---------------- Pool ----------------
__device__ int lower_bound_dev(const int* a, int n, int v) {
    int lo = 0, hi = n;
    while (lo < hi) {
        int mid = (lo + hi) >> 1;
        if (a[mid] < v) lo = mid + 1; else hi = mid;
    }
    return lo;
}

__global__ __launch_bounds__(256) void pool_kernel(const float* __restrict__ h,
                                                   const int* __restrict__ batch, int N,
                                                   float* __restrict__ g) {
    __shared__ int sh[2];
    if (threadIdx.x == 0) {
        sh[0] = lower_bound_dev(batch, N, (int)blockIdx.x);
        sh[1] = lower_bound_dev(batch, N, (int)blockIdx.x + 1);
    }
    __syncthreads();
    int s0 = sh[0], s1 = sh[1];
    float s = 0.f;
    for (int r = s0; r < s1; ++r) s += h[r * 256 + threadIdx.x];
    float cnt = (float)(s1 - s0);
    g[blockIdx.x * 256 + threadIdx.x] = s / fmaxf(cnt, 1.0f);
}

// ---------------- MLP ----------------
__global__ void mlp_gemm(const float* __restrict__ in, const float* __restrict__ W,
                         float* __restrict__ outp, int K, int C) {
    extern __shared__ float srow[];
    int r = blockIdx.x;
    for (int k = threadIdx.x; k < K; k += blockDim.x) srow[k] = in[r * K + k];
    __syncthreads();
    int c = threadIdx.x;
    float acc = 0.f;
    for (int k = 0; k < K; ++k) acc = fmaf(srow[k], W[k * C + c], acc);
    outp[r * C + c] = acc;
}

__global__ void final_gemm(const float* __restrict__ z2, const float* __restrict__ w3,
                           const float* __restrict__ b3, float* __restrict__ outp, int G) {
    int g = blockIdx.x * blockDim.x + threadIdx.x;
    if (g >= G) return;
    float acc = b3[0];
    for (int k = 0; k < 64; ++k) acc = fmaf(z2[g * 64 + k], w3[k], acc);
    outp[g] = acc;
}

extern "C" void kernel_launch(void* const* d_in, const int* in_sizes, int n_in,
                              void* d_out, int out_size, void* d_ws, size_t ws_size,
                              hipStream_t stream) {
    const float* atom_emb = (const float*)d_in[0];
    const float* bases_W = (const float*)d_in[1];
    const float* comb_W = (const float*)d_in[2];
    const float* comb_b = (const float*)d_in[3];
    const float* conv_bias = (const float*)d_in[4];
    const float* bn_gamma = (const float*)d_in[5];
    const float* bn_beta = (const float*)d_in[6];
    const float* w1 = (const float*)d_in[7];
    const float* g1 = (const float*)d_in[8];
    const float* b1 = (const float*)d_in[9];
    const float* w2 = (const float*)d_in[10];
    const float* g2 = (const float*)d_in[11];
    const float* b2 = (const float*)d_in[12];
    const float* w3 = (const float*)d_in[13];
    const float* b3 = (const float*)d_in[14];
    const int* x = (const int*)d_in[15];
    const int* edge_index = (const int*)d_in[16];
    const int* batch = (const int*)d_in[17];
    float* out = (float*)d_out;

    const int N = in_sizes[15] / 9;
    const int E = in_sizes[16] / 2;
    const int G = NGRAPH;

    // workspace carve
    char* p = (char*)d_ws;
    auto alloc = [&](size_t bytes) -> void* {
        void* r = (void*)p;
        p += (bytes + 255) & ~(size_t)255;
        return r;
    };
    float* h = (float*)alloc((size_t)N * 256 * 4);
    short* hb = (short*)alloc((size_t)N * 256 * 2);
    float* outb = (float*)alloc((size_t)N * 256 * 4);
    short* bases = (short*)alloc((size_t)N * 128 * 2);
    float* wts = (float*)alloc((size_t)N * 96 * 4);
    short* WT = (short*)alloc((size_t)4 * 224 * 256 * 2);
    int* row_ptr = (int*)alloc((size_t)(N + 1) * 4);
    int* cnt = (int*)alloc((size_t)N * 4);  // reused as woff
    int* srcs = (int*)alloc((size_t)(E + N) * 4);
    float* partial = (float*)alloc((size_t)256 * 2 * 256 * 4);
    float* ss = (float*)alloc((size_t)2 * 256 * 4);
    float* g = (float*)alloc((size_t)G * 256 * 4);
    float* z1 = (float*)alloc((size_t)G * 128 * 4);
    float* z2 = (float*)alloc((size_t)G * 64 * 4);

    // atom encoder + weight prep
    atom_enc<<<N, 256, 0, stream>>>(x, atom_emb, h, hb, N);
    prep_wt<<<4 * 224, 256, 0, stream>>>(bases_W, comb_W, WT);

    // CSR build
    init_cnt<<<(N + 255) / 256, 256, 0, stream>>>(cnt, N);
    csr_count<<<(E + 255) / 256, 256, 0, stream>>>(edge_index, E, cnt);
    scan_kernel<<<1, 1024, 0, stream>>>(cnt, row_ptr, N);
    copy_woff<<<(N + 255) / 256, 256, 0, stream>>>(row_ptr, cnt, N);
    csr_scatter<<<(E + N + 255) / 256, 256, 0, stream>>>(edge_index, E, N, cnt, srcs);

    const int NB = 240;
    for (int l = 0; l < 4; ++l) {
        const short* WTl = WT + (size_t)l * 224 * 256;
        const float* cb = comb_b + (size_t)l * 96;
        const float* cbias = conv_bias + (size_t)l * 256;
        const float* gam = bn_gamma + (size_t)l * 256;
        const float* bet = bn_beta + (size_t)l * 256;

        gemm_mfma<<<(N + 63) / 64, 256, 0, stream>>>(hb, WTl, cb, bases, wts, N);
        agg_einsum<<<(N + 3) / 4, 256, 0, stream>>>(bases, wts, row_ptr, srcs, cbias, outb, N);
        bn_stats<<<NB, 256, 0, stream>>>(outb, N, 256, partial);
        bn_finalize<<<1, 256, 0, stream>>>(partial, NB, 256, N, gam, bet, ss);
        int total4 = N * 256 / 4;
        bn_apply_res4<<<(total4 + 255) / 256, 256, 0, stream>>>((float4*)h, (const float4*)outb, ss, hb, total4);
    }

    // pool
    pool_kernel<<<G, 256, 0, stream>>>(h, batch, N, g);

    // MLP layer 1: 256 -> 128
    mlp_gemm<<<G, 128, 256 * 4, stream>>>(g, w1, z1, 256, 128);
    bn_stats<<<64, 128, 0, stream>>>(z1, G, 128, partial);
    bn_finalize<<<1, 128, 0, stream>>>(partial, 64, 128, G, g1, b1, ss);
    bn_apply<<<(G * 128 + 255) / 256, 256, 0, stream>>>(z1, ss, G * 128, 128, 127);

    // MLP layer 2: 128 -> 64
    mlp_gemm<<<G, 64, 128 * 4, stream>>>(z1, w2, z2, 128, 64);
    bn_stats<<<64, 64, 0, stream>>>(z2, G, 64, partial);
    bn_finalize<<<1, 64, 0, stream>>>(partial, 64, 64, G, g2, b2, ss);
    bn_apply<<<(G * 64 + 255) / 256, 256, 0, stream>>>(z2, ss, G * 64, 64, 63);

    // final: 64 -> 1
    final_gemm<<<(G + 255) / 256, 256, 0, stream>>>(z2, w3, b3, out, G);
}

// Round 3
// 1193.039 us; speedup vs baseline: 2.3345x; 1.3624x over previous
//
#include <hip/hip_runtime.h>
#include <hip/hip_bf16.h>

#define HID 256
#define NGRAPH 2048

typedef __attribute__((ext_vector_type(8))) short s16x8;
typedef __attribute__((ext_vector_type(4))) float f32x4v;

__device__ inline short f2b(float f) {
    __hip_bfloat16 b = __float2bfloat16(f);
    return *reinterpret_cast<short*>(&b);
}
__device__ inline float b2f_lo(unsigned int v) {
    return __uint_as_float(v << 16);
}
__device__ inline float b2f_hi(unsigned int v) {
    return __uint_as_float(v & 0xffff0000u);
}

// ---------------- Atom encoder: h fp32 + bf16 mirror ----------------
__global__ __launch_bounds__(256) void atom_enc(const int* __restrict__ x,
                                                const float* __restrict__ emb,
                                                float* __restrict__ h,
                                                short* __restrict__ hb, int N) {
    int n = blockIdx.x;
    int c = threadIdx.x;
    if (n >= N) return;
    const int offs[9] = {0, 119, 124, 136, 148, 158, 164, 170, 172};
    float s = 0.f;
#pragma unroll
    for (int j = 0; j < 9; ++j) {
        int row = x[n * 9 + j] + offs[j];
        s += emb[row * 256 + c];
    }
    h[n * 256 + c] = s;
    hb[n * 256 + c] = f2b(s);
}

// ---------------- Weight prep: combined [224][256] bf16 transposed, per layer ----------------
__global__ void prep_wt(const float* __restrict__ bases_W, const float* __restrict__ comb_W,
                        short* __restrict__ WT) {
    int l = blockIdx.x / 224;
    int n = blockIdx.x % 224;
    int k = threadIdx.x;  // 0..255
    float v = (n < 128) ? bases_W[((size_t)l * 256 + k) * 128 + n]
                        : comb_W[((size_t)l * 256 + k) * 96 + (n - 128)];
    WT[((size_t)l * 224 + n) * 256 + k] = f2b(v);
}

// ---------------- CSR build ----------------
__global__ void init_cnt(int* cnt, int N) {
    int i = blockIdx.x * blockDim.x + threadIdx.x;
    if (i < N) cnt[i] = 1;  // self loop
}

__global__ void csr_count(const int* __restrict__ ei, int E, int* cnt) {
    int e = blockIdx.x * blockDim.x + threadIdx.x;
    if (e >= E) return;
    atomicAdd(&cnt[ei[e]], 1);
}

__global__ __launch_bounds__(1024) void scan_kernel(const int* __restrict__ cnt,
                                                    int* __restrict__ row_ptr, int N) {
    __shared__ int buf[1024];
    __shared__ int carry;
    if (threadIdx.x == 0) carry = 0;
    __syncthreads();
    for (int base = 0; base < N; base += 1024) {
        int i = base + threadIdx.x;
        int v = (i < N) ? cnt[i] : 0;
        buf[threadIdx.x] = v;
        __syncthreads();
        for (int off = 1; off < 1024; off <<= 1) {
            int t = (threadIdx.x >= off) ? buf[threadIdx.x - off] : 0;
            __syncthreads();
            buf[threadIdx.x] += t;
            __syncthreads();
        }
        int incl = buf[threadIdx.x];
        int excl = incl - v;
        int c = carry;
        if (i < N) row_ptr[i] = c + excl;
        int total = buf[1023];
        __syncthreads();
        if (threadIdx.x == 0) carry = c + total;
        __syncthreads();
    }
    if (threadIdx.x == 0) row_ptr[N] = carry;
}

__global__ void copy_woff(const int* __restrict__ row_ptr, int* __restrict__ woff, int N) {
    int i = blockIdx.x * blockDim.x + threadIdx.x;
    if (i < N) woff[i] = row_ptr[i];
}

__global__ void csr_scatter(const int* __restrict__ ei, int E, int N,
                            int* __restrict__ woff, int* __restrict__ srcs) {
    int i = blockIdx.x * blockDim.x + threadIdx.x;
    if (i >= E + N) return;
    int d, s;
    if (i < E) { d = ei[i]; s = ei[E + i]; }
    else       { d = i - E; s = i - E; }
    int pos = atomicAdd(&woff[d], 1);
    srcs[pos] = s;
}

// ---------------- MFMA GEMM v2: LDS-staged B, double-buffered ----------------
// hb[N,256] @ WT^T -> bases bf16 [N,128], wts fp32 [N,96]
// 4 waves/block, 16 rows/wave (BM=64). B staged in 32-col tiles (7 tiles).
// LDS tile layout: [col][k] shorts, col stride 512B, XOR-swizzled by (col&7)<<4.
__global__ __launch_bounds__(256) void gemm_mfma(const short* __restrict__ hb,
                                                 const short* __restrict__ WT,
                                                 const float* __restrict__ cb,
                                                 short* __restrict__ bases,
                                                 float* __restrict__ wts, int N) {
    __shared__ short bs[2][32 * 256];  // 2 x 16KB
    int tid = threadIdx.x;
    int wid = tid >> 6;
    int lane = tid & 63;
    int m0 = blockIdx.x * 64 + wid * 16;
    int row_a = m0 + (lane & 15);
    if (row_a > N - 1) row_a = N - 1;
    int kgrp = (lane >> 4) * 8;  // 0,8,16,24

    // A: whole K=256 strip for this row
    s16x8 a[8];
#pragma unroll
    for (int i = 0; i < 8; ++i)
        a[i] = *(const s16x8*)&hb[(size_t)row_a * 256 + i * 32 + kgrp];

    // staging geometry: thread -> col = tid>>3 (0..31), kk = (tid&7)*32
    int st_col = tid >> 3;
    int st_kk = (tid & 7) * 32;
    int st_sw = (st_col & 7) << 4;
    int st_base = st_col * 512 + st_kk * 2;  // byte offset in tile

    auto stage = [&](int buf, int t) {
        const s16x8* src = (const s16x8*)&WT[(size_t)(t * 32 + st_col) * 256 + st_kk];
        char* dst = (char*)bs[buf];
#pragma unroll
        for (int q = 0; q < 4; ++q)
            *(s16x8*)(dst + ((st_base + q * 16) ^ st_sw)) = src[q];
    };

    stage(0, 0);

    int col = lane & 15;
    int rd_base = col * 512 + (lane >> 4) * 16;
    int rd_sw = (col & 7) << 4;
    int rbase = m0 + (lane >> 4) * 4;

    for (int t = 0; t < 7; ++t) {
        __syncthreads();
        if (t + 1 < 7) stage((t + 1) & 1, t + 1);

        const char* base = (const char*)bs[t & 1];
        f32x4v c0 = {0.f, 0.f, 0.f, 0.f};
        f32x4v c1 = {0.f, 0.f, 0.f, 0.f};
#pragma unroll
        for (int i = 0; i < 8; ++i) {
            s16x8 b0 = *(const s16x8*)(base + ((rd_base + i * 64) ^ rd_sw));
            s16x8 b1 = *(const s16x8*)(base + ((rd_base + 8192 + i * 64) ^ rd_sw));
            c0 = __builtin_amdgcn_mfma_f32_16x16x32_bf16(a[i], b0, c0, 0, 0, 0);
            c1 = __builtin_amdgcn_mfma_f32_16x16x32_bf16(a[i], b1, c1, 0, 0, 0);
        }

        // epilogue for cols cc0 = t*32+col, cc1 = cc0+16
        int cc0 = t * 32 + col;
        int cc1 = cc0 + 16;
        float cb0 = (cc0 >= 128) ? cb[cc0 - 128] : 0.f;
        float cb1 = (cc1 >= 128) ? cb[cc1 - 128] : 0.f;
#pragma unroll
        for (int r = 0; r < 4; ++r) {
            int row = rbase + r;
            if (row >= N) continue;
            float v0 = c0[r], v1 = c1[r];
            if (cc0 < 128) bases[(size_t)row * 128 + cc0] = f2b(v0);
            else wts[(size_t)row * 96 + (cc0 - 128)] = v0 + cb0;
            if (cc1 < 128) bases[(size_t)row * 128 + cc1] = f2b(v1);
            else wts[(size_t)row * 96 + (cc1 - 128)] = v1 + cb1;
        }
    }
}

// ---------------- Aggregation (sum/mean/max) + einsum + conv_bias ----------------
// one wave per node; block = 4 waves; bases is bf16 (2 cols/lane); edge loop x4 unrolled
__global__ __launch_bounds__(256) void agg_einsum(const short* __restrict__ bases,
                                                  const float* __restrict__ wts,
                                                  const int* __restrict__ row_ptr,
                                                  const int* __restrict__ srcs,
                                                  const float* __restrict__ cbias,
                                                  float* __restrict__ outp, int N) {
    __shared__ float agg_lds[4][3][128];
    __shared__ float wts_lds[4][96];
    int wid = threadIdx.x >> 6;
    int lane = threadIdx.x & 63;
    int n = blockIdx.x * 4 + wid;
    bool valid = (n < N);
    if (valid) {
        int r0 = row_ptr[n];
        int r1 = row_ptr[n + 1];
        const short* bp = bases + 2 * lane;
        float sx0 = 0.f, sy0 = 0.f, sx1 = 0.f, sy1 = 0.f;
        float sx2 = 0.f, sy2 = 0.f, sx3 = 0.f, sy3 = 0.f;
        const float NI = -3.402823466e+38f;
        float mx0 = NI, my0 = NI, mx1 = NI, my1 = NI;
        float mx2 = NI, my2 = NI, mx3 = NI, my3 = NI;
        int r = r0;
        for (; r + 3 < r1; r += 4) {
            int s0 = srcs[r], s1 = srcs[r + 1], s2 = srcs[r + 2], s3 = srcs[r + 3];
            unsigned int v0 = *(const unsigned int*)&bp[(size_t)s0 * 128];
            unsigned int v1 = *(const unsigned int*)&bp[(size_t)s1 * 128];
            unsigned int v2 = *(const unsigned int*)&bp[(size_t)s2 * 128];
            unsigned int v3 = *(const unsigned int*)&bp[(size_t)s3 * 128];
            float f0x = b2f_lo(v0), f0y = b2f_hi(v0);
            float f1x = b2f_lo(v1), f1y = b2f_hi(v1);
            float f2x = b2f_lo(v2), f2y = b2f_hi(v2);
            float f3x = b2f_lo(v3), f3y = b2f_hi(v3);
            sx0 += f0x; sy0 += f0y; mx0 = fmaxf(mx0, f0x); my0 = fmaxf(my0, f0y);
            sx1 += f1x; sy1 += f1y; mx1 = fmaxf(mx1, f1x); my1 = fmaxf(my1, f1y);
            sx2 += f2x; sy2 += f2y; mx2 = fmaxf(mx2, f2x); my2 = fmaxf(my2, f2y);
            sx3 += f3x; sy3 += f3y; mx3 = fmaxf(mx3, f3x); my3 = fmaxf(my3, f3y);
        }
        for (; r < r1; ++r) {
            int s0 = srcs[r];
            unsigned int v0 = *(const unsigned int*)&bp[(size_t)s0 * 128];
            float f0x = b2f_lo(v0), f0y = b2f_hi(v0);
            sx0 += f0x; sy0 += f0y; mx0 = fmaxf(mx0, f0x); my0 = fmaxf(my0, f0y);
        }
        float sx = (sx0 + sx1) + (sx2 + sx3);
        float sy = (sy0 + sy1) + (sy2 + sy3);
        float mx = fmaxf(fmaxf(mx0, mx1), fmaxf(mx2, mx3));
        float my = fmaxf(fmaxf(my0, my1), fmaxf(my2, my3));
        float inv = 1.0f / (float)(r1 - r0);
        agg_lds[wid][0][2 * lane] = sx;       agg_lds[wid][0][2 * lane + 1] = sy;
        agg_lds[wid][1][2 * lane] = sx * inv; agg_lds[wid][1][2 * lane + 1] = sy * inv;
        agg_lds[wid][2][2 * lane] = mx;       agg_lds[wid][2][2 * lane + 1] = my;
        wts_lds[wid][lane] = wts[(size_t)n * 96 + lane];
        if (lane < 32) wts_lds[wid][64 + lane] = wts[(size_t)n * 96 + 64 + lane];
    }
    __syncthreads();
    if (valid) {
#pragma unroll
        for (int j = 0; j < 4; ++j) {
            int o = lane + 64 * j;
            int hh = o >> 5;
            int d = o & 31;
            float acc = cbias[o];
#pragma unroll
            for (int k = 0; k < 12; ++k)
                acc = fmaf(wts_lds[wid][hh * 12 + k], agg_lds[wid][k >> 2][(k & 3) * 32 + d], acc);
            outp[n * 256 + o] = acc;
        }
    }
}

// ---------------- BN (2-stage, deterministic) ----------------
__global__ void bn_stats(const float* __restrict__ v, int N, int C, float* __restrict__ partial) {
    int c = threadIdx.x;  // blockDim == C
    float s = 0.f, s2 = 0.f;
    for (int r = blockIdx.x; r < N; r += gridDim.x) {
        float t = v[r * C + c];
        s += t; s2 += t * t;
    }
    partial[(blockIdx.x * 2 + 0) * C + c] = s;
    partial[(blockIdx.x * 2 + 1) * C + c] = s2;
}

__global__ void bn_finalize(const float* __restrict__ partial, int NB, int C, int N,
                            const float* __restrict__ gamma, const float* __restrict__ beta,
                            float* __restrict__ ss) {
    int c = threadIdx.x;
    if (c >= C) return;
    float s = 0.f, s2 = 0.f;
    for (int b = 0; b < NB; ++b) {
        s += partial[(b * 2 + 0) * C + c];
        s2 += partial[(b * 2 + 1) * C + c];
    }
    float invN = 1.0f / (float)N;
    float mu = s * invN;
    float var = fmaxf(s2 * invN - mu * mu, 0.f);
    float sc = gamma[c] * rsqrtf(var + 1e-5f);
    ss[c] = sc;
    ss[C + c] = beta[c] - mu * sc;
}

// h += relu(out*sc+sh), C=256, vectorized x4; also writes bf16 mirror of h
__global__ void bn_apply_res4(float4* __restrict__ h, const float4* __restrict__ outp,
                              const float* __restrict__ ss, short* __restrict__ hb, int total4) {
    int i = blockIdx.x * blockDim.x + threadIdx.x;
    if (i >= total4) return;
    int c0 = (i * 4) & 255;
    float4 o = outp[i];
    float4 hv = h[i];
    hv.x += fmaxf(o.x * ss[c0 + 0] + ss[256 + c0 + 0], 0.f);
    hv.y += fmaxf(o.y * ss[c0 + 1] + ss[256 + c0 + 1], 0.f);
    hv.z += fmaxf(o.z * ss[c0 + 2] + ss[256 + c0 + 2], 0.f);
    hv.w += fmaxf(o.w * ss[c0 + 3] + ss[256 + c0 + 3], 0.f);
    h[i] = hv;
    short4 hb4;
    hb4.x = f2b(hv.x); hb4.y = f2b(hv.y); hb4.z = f2b(hv.z); hb4.w = f2b(hv.w);
    *(short4*)&hb[(size_t)i * 4] = hb4;
}

// z = relu(z*sc+sh), in place, C power of 2
__global__ void bn_apply(float* __restrict__ z, const float* __restrict__ ss, int total, int C, int Cmask) {
    int i = blockIdx.x * blockDim.x + threadIdx.x;
    if (i >= total) return;
    int c = i & Cmask;
    z[i] = fmaxf(z[i] * ss[c] + ss[C + c], 0.f);
}

// ---------------- Pool ----------------
__device__ int lower_bound_dev(const int* a, int n, int v) {
    int lo = 0, hi = n;
    while (lo < hi) {
        int mid = (lo + hi) >> 1;
        if (a[mid] < v) lo = mid + 1; else hi = mid;
    }
    return lo;
}

__global__ __launch_bounds__(256) void pool_kernel(const float* __restrict__ h,
                                                   const int* __restrict__ batch, int N,
                                                   float* __restrict__ g) {
    __shared__ int sh[2];
    if (threadIdx.x == 0) {
        sh[0] = lower_bound_dev(batch, N, (int)blockIdx.x);
        sh[1] = lower_bound_dev(batch, N, (int)blockIdx.x + 1);
    }
    __syncthreads();
    int s0 = sh[0], s1 = sh[1];
    float s = 0.f;
    for (int r = s0; r < s1; ++r) s += h[r * 256 + threadIdx.x];
    float cnt = (float)(s1 - s0);
    g[blockIdx.x * 256 + threadIdx.x] = s / fmaxf(cnt, 1.0f);
}

// ---------------- MLP ----------------
__global__ void mlp_gemm(const float* __restrict__ in, const float* __restrict__ W,
                         float* __restrict__ outp, int K, int C) {
    extern __shared__ float srow[];
    int r = blockIdx.x;
    for (int k = threadIdx.x; k < K; k += blockDim.x) srow[k] = in[r * K + k];
    __syncthreads();
    int c = threadIdx.x;
    float acc = 0.f;
    for (int k = 0; k < K; ++k) acc = fmaf(srow[k], W[k * C + c], acc);
    outp[r * C + c] = acc;
}

__global__ void final_gemm(const float* __restrict__ z2, const float* __restrict__ w3,
                           const float* __restrict__ b3, float* __restrict__ outp, int G) {
    int g = blockIdx.x * blockDim.x + threadIdx.x;
    if (g >= G) return;
    float acc = b3[0];
    for (int k = 0; k < 64; ++k) acc = fmaf(z2[g * 64 + k], w3[k], acc);
    outp[g] = acc;
}

extern "C" void kernel_launch(void* const* d_in, const int* in_sizes, int n_in,
                              void* d_out, int out_size, void* d_ws, size_t ws_size,
                              hipStream_t stream) {
    const float* atom_emb = (const float*)d_in[0];
    const float* bases_W = (const float*)d_in[1];
    const float* comb_W = (const float*)d_in[2];
    const float* comb_b = (const float*)d_in[3];
    const float* conv_bias = (const float*)d_in[4];
    const float* bn_gamma = (const float*)d_in[5];
    const float* bn_beta = (const float*)d_in[6];
    const float* w1 = (const float*)d_in[7];
    const float* g1 = (const float*)d_in[8];
    const float* b1 = (const float*)d_in[9];
    const float* w2 = (const float*)d_in[10];
    const float* g2 = (const float*)d_in[11];
    const float* b2 = (const float*)d_in[12];
    const float* w3 = (const float*)d_in[13];
    const float* b3 = (const float*)d_in[14];
    const int* x = (const int*)d_in[15];
    const int* edge_index = (const int*)d_in[16];
    const int* batch = (const int*)d_in[17];
    float* out = (float*)d_out;

    const int N = in_sizes[15] / 9;
    const int E = in_sizes[16] / 2;
    const int G = NGRAPH;

    // workspace carve
    char* p = (char*)d_ws;
    auto alloc = [&](size_t bytes) -> void* {
        void* r = (void*)p;
        p += (bytes + 255) & ~(size_t)255;
        return r;
    };
    float* h = (float*)alloc((size_t)N * 256 * 4);
    short* hb = (short*)alloc((size_t)N * 256 * 2);
    float* outb = (float*)alloc((size_t)N * 256 * 4);
    short* bases = (short*)alloc((size_t)N * 128 * 2);
    float* wts = (float*)alloc((size_t)N * 96 * 4);
    short* WT = (short*)alloc((size_t)4 * 224 * 256 * 2);
    int* row_ptr = (int*)alloc((size_t)(N + 1) * 4);
    int* cnt = (int*)alloc((size_t)N * 4);  // reused as woff
    int* srcs = (int*)alloc((size_t)(E + N) * 4);
    float* partial = (float*)alloc((size_t)256 * 2 * 256 * 4);
    float* ss = (float*)alloc((size_t)2 * 256 * 4);
    float* g = (float*)alloc((size_t)G * 256 * 4);
    float* z1 = (float*)alloc((size_t)G * 128 * 4);
    float* z2 = (float*)alloc((size_t)G * 64 * 4);

    // atom encoder + weight prep
    atom_enc<<<N, 256, 0, stream>>>(x, atom_emb, h, hb, N);
    prep_wt<<<4 * 224, 256, 0, stream>>>(bases_W, comb_W, WT);

    // CSR build
    init_cnt<<<(N + 255) / 256, 256, 0, stream>>>(cnt, N);
    csr_count<<<(E + 255) / 256, 256, 0, stream>>>(edge_index, E, cnt);
    scan_kernel<<<1, 1024, 0, stream>>>(cnt, row_ptr, N);
    copy_woff<<<(N + 255) / 256, 256, 0, stream>>>(row_ptr, cnt, N);
    csr_scatter<<<(E + N + 255) / 256, 256, 0, stream>>>(edge_index, E, N, cnt, srcs);

    const int NB = 240;
    for (int l = 0; l < 4; ++l) {
        const short* WTl = WT + (size_t)l * 224 * 256;
        const float* cb = comb_b + (size_t)l * 96;
        const float* cbias = conv_bias + (size_t)l * 256;
        const float* gam = bn_gamma + (size_t)l * 256;
        const float* bet = bn_beta + (size_t)l * 256;

        gemm_mfma<<<(N + 63) / 64, 256, 0, stream>>>(hb, WTl, cb, bases, wts, N);
        agg_einsum<<<(N + 3) / 4, 256, 0, stream>>>(bases, wts, row_ptr, srcs, cbias, outb, N);
        bn_stats<<<NB, 256, 0, stream>>>(outb, N, 256, partial);
        bn_finalize<<<1, 256, 0, stream>>>(partial, NB, 256, N, gam, bet, ss);
        int total4 = N * 256 / 4;
        bn_apply_res4<<<(total4 + 255) / 256, 256, 0, stream>>>((float4*)h, (const float4*)outb, ss, hb, total4);
    }

    // pool
    pool_kernel<<<G, 256, 0, stream>>>(h, batch, N, g);

    // MLP layer 1: 256 -> 128
    mlp_gemm<<<G, 128, 256 * 4, stream>>>(g, w1, z1, 256, 128);
    bn_stats<<<64, 128, 0, stream>>>(z1, G, 128, partial);
    bn_finalize<<<1, 128, 0, stream>>>(partial, 64, 128, G, g1, b1, ss);
    bn_apply<<<(G * 128 + 255) / 256, 256, 0, stream>>>(z1, ss, G * 128, 128, 127);

    // MLP layer 2: 128 -> 64
    mlp_gemm<<<G, 64, 128 * 4, stream>>>(z1, w2, z2, 128, 64);
    bn_stats<<<64, 64, 0, stream>>>(z2, G, 64, partial);
    bn_finalize<<<1, 64, 0, stream>>>(partial, 64, 64, G, g2, b2, ss);
    bn_apply<<<(G * 64 + 255) / 256, 256, 0, stream>>>(z2, ss, G * 64, 64, 63);

    // final: 64 -> 1
    final_gemm<<<(G + 255) / 256, 256, 0, stream>>>(z2, w3, b3, out, G);
}

// Round 4
// 1035.988 us; speedup vs baseline: 2.6884x; 1.1516x over previous
//
#include <hip/hip_runtime.h>
#include <hip/hip_bf16.h>

#define HID 256
#define NGRAPH 2048

typedef __attribute__((ext_vector_type(8))) short s16x8;
typedef __attribute__((ext_vector_type(4))) float f32x4v;

__device__ inline short f2b(float f) {
    __hip_bfloat16 b = __float2bfloat16(f);
    return *reinterpret_cast<short*>(&b);
}
__device__ inline float b2f_lo(unsigned int v) {
    return __uint_as_float(v << 16);
}
__device__ inline float b2f_hi(unsigned int v) {
    return __uint_as_float(v & 0xffff0000u);
}

// ---------------- Atom encoder: h fp32 + bf16 mirror ----------------
__global__ __launch_bounds__(256) void atom_enc(const int* __restrict__ x,
                                                const float* __restrict__ emb,
                                                float* __restrict__ h,
                                                short* __restrict__ hb, int N) {
    int n = blockIdx.x;
    int c = threadIdx.x;
    if (n >= N) return;
    const int offs[9] = {0, 119, 124, 136, 148, 158, 164, 170, 172};
    float s = 0.f;
#pragma unroll
    for (int j = 0; j < 9; ++j) {
        int row = x[n * 9 + j] + offs[j];
        s += emb[row * 256 + c];
    }
    h[n * 256 + c] = s;
    hb[n * 256 + c] = f2b(s);
}

// ---------------- Weight prep ----------------
__global__ void prep_wt(const float* __restrict__ bases_W, const float* __restrict__ comb_W,
                        short* __restrict__ WT) {
    int l = blockIdx.x / 224;
    int n = blockIdx.x % 224;
    int k = threadIdx.x;  // 0..255
    float v = (n < 128) ? bases_W[((size_t)l * 256 + k) * 128 + n]
                        : comb_W[((size_t)l * 256 + k) * 96 + (n - 128)];
    WT[((size_t)l * 224 + n) * 256 + k] = f2b(v);
}

// ---------------- CSR build ----------------
__global__ void init_cnt(int* cnt, int N) {
    int i = blockIdx.x * blockDim.x + threadIdx.x;
    if (i < N) cnt[i] = 1;  // self loop
}

__global__ void csr_count(const int* __restrict__ ei, int E, int* cnt) {
    int e = blockIdx.x * blockDim.x + threadIdx.x;
    if (e >= E) return;
    atomicAdd(&cnt[ei[e]], 1);
}

// hierarchical scan: S1 per-1024-chunk sums
__global__ __launch_bounds__(256) void scan_s1(const int* __restrict__ cnt, int* __restrict__ blksum, int N) {
    __shared__ int red[256];
    int base = blockIdx.x * 1024;
    int s = 0;
#pragma unroll
    for (int q = 0; q < 4; ++q) {
        int i = base + threadIdx.x * 4 + q;
        s += (i < N) ? cnt[i] : 0;
    }
    red[threadIdx.x] = s;
    __syncthreads();
    for (int off = 128; off > 0; off >>= 1) {
        if (threadIdx.x < off) red[threadIdx.x] += red[threadIdx.x + off];
        __syncthreads();
    }
    if (threadIdx.x == 0) blksum[blockIdx.x] = red[0];
}

// S2: exclusive scan of block sums (nb <= 256), also writes total to row_ptr[N]
__global__ __launch_bounds__(256) void scan_s2(int* __restrict__ blksum, int nb, int* __restrict__ row_ptr, int N) {
    __shared__ int buf[256];
    int v = (threadIdx.x < nb) ? blksum[threadIdx.x] : 0;
    buf[threadIdx.x] = v;
    __syncthreads();
    for (int off = 1; off < 256; off <<= 1) {
        int t = (threadIdx.x >= off) ? buf[threadIdx.x - off] : 0;
        __syncthreads();
        buf[threadIdx.x] += t;
        __syncthreads();
    }
    if (threadIdx.x < nb) blksum[threadIdx.x] = buf[threadIdx.x] - v;  // exclusive
    if (threadIdx.x == 0) row_ptr[N] = buf[255];
}

// S3: per-chunk local scan + base; writes row_ptr and woff
__global__ __launch_bounds__(256) void scan_s3(const int* __restrict__ cnt, const int* __restrict__ blksum,
                                               int* __restrict__ row_ptr, int* __restrict__ woff, int N) {
    __shared__ int buf[256];
    int base = blockIdx.x * 1024;
    int i0 = base + threadIdx.x * 4;
    int v[4];
    int s = 0;
#pragma unroll
    for (int q = 0; q < 4; ++q) {
        int i = i0 + q;
        v[q] = (i < N) ? cnt[i] : 0;
        s += v[q];
    }
    buf[threadIdx.x] = s;
    __syncthreads();
    for (int off = 1; off < 256; off <<= 1) {
        int t = (threadIdx.x >= off) ? buf[threadIdx.x - off] : 0;
        __syncthreads();
        buf[threadIdx.x] += t;
        __syncthreads();
    }
    int excl = buf[threadIdx.x] - s + blksum[blockIdx.x];
#pragma unroll
    for (int q = 0; q < 4; ++q) {
        int i = i0 + q;
        if (i < N) { row_ptr[i] = excl; woff[i] = excl; }
        excl += v[q];
    }
}

__global__ void csr_scatter(const int* __restrict__ ei, int E, int N,
                            int* __restrict__ woff, int* __restrict__ srcs) {
    int i = blockIdx.x * blockDim.x + threadIdx.x;
    if (i >= E + N) return;
    int d, s;
    if (i < E) { d = ei[i]; s = ei[E + i]; }
    else       { d = i - E; s = i - E; }
    int pos = atomicAdd(&woff[d], 1);
    srcs[pos] = s;
}

// ---------------- MFMA GEMM: LDS-staged B, double-buffered ----------------
__global__ __launch_bounds__(256) void gemm_mfma(const short* __restrict__ hb,
                                                 const short* __restrict__ WT,
                                                 const float* __restrict__ cb,
                                                 short* __restrict__ bases,
                                                 float* __restrict__ wts, int N) {
    __shared__ short bs[2][32 * 256];  // 2 x 16KB
    int tid = threadIdx.x;
    int wid = tid >> 6;
    int lane = tid & 63;
    int m0 = blockIdx.x * 64 + wid * 16;
    int row_a = m0 + (lane & 15);
    if (row_a > N - 1) row_a = N - 1;
    int kgrp = (lane >> 4) * 8;  // 0,8,16,24

    s16x8 a[8];
#pragma unroll
    for (int i = 0; i < 8; ++i)
        a[i] = *(const s16x8*)&hb[(size_t)row_a * 256 + i * 32 + kgrp];

    int st_col = tid >> 3;
    int st_kk = (tid & 7) * 32;
    int st_sw = (st_col & 7) << 4;
    int st_base = st_col * 512 + st_kk * 2;

    auto stage = [&](int buf, int t) {
        const s16x8* src = (const s16x8*)&WT[(size_t)(t * 32 + st_col) * 256 + st_kk];
        char* dst = (char*)bs[buf];
#pragma unroll
        for (int q = 0; q < 4; ++q)
            *(s16x8*)(dst + ((st_base + q * 16) ^ st_sw)) = src[q];
    };

    stage(0, 0);

    int col = lane & 15;
    int rd_base = col * 512 + (lane >> 4) * 16;
    int rd_sw = (col & 7) << 4;
    int rbase = m0 + (lane >> 4) * 4;

    for (int t = 0; t < 7; ++t) {
        __syncthreads();
        if (t + 1 < 7) stage((t + 1) & 1, t + 1);

        const char* base = (const char*)bs[t & 1];
        f32x4v c0 = {0.f, 0.f, 0.f, 0.f};
        f32x4v c1 = {0.f, 0.f, 0.f, 0.f};
#pragma unroll
        for (int i = 0; i < 8; ++i) {
            s16x8 b0 = *(const s16x8*)(base + ((rd_base + i * 64) ^ rd_sw));
            s16x8 b1 = *(const s16x8*)(base + ((rd_base + 8192 + i * 64) ^ rd_sw));
            c0 = __builtin_amdgcn_mfma_f32_16x16x32_bf16(a[i], b0, c0, 0, 0, 0);
            c1 = __builtin_amdgcn_mfma_f32_16x16x32_bf16(a[i], b1, c1, 0, 0, 0);
        }

        int cc0 = t * 32 + col;
        int cc1 = cc0 + 16;
        float cb0 = (cc0 >= 128) ? cb[cc0 - 128] : 0.f;
        float cb1 = (cc1 >= 128) ? cb[cc1 - 128] : 0.f;
#pragma unroll
        for (int r = 0; r < 4; ++r) {
            int row = rbase + r;
            if (row >= N) continue;
            float v0 = c0[r], v1 = c1[r];
            if (cc0 < 128) bases[(size_t)row * 128 + cc0] = f2b(v0);
            else wts[(size_t)row * 96 + (cc0 - 128)] = v0 + cb0;
            if (cc1 < 128) bases[(size_t)row * 128 + cc1] = f2b(v1);
            else wts[(size_t)row * 96 + (cc1 - 128)] = v1 + cb1;
        }
    }
}

// ---------------- Aggregation v3: shfl-batched srcs, unroll 8, wave-sync ----------------
__global__ __launch_bounds__(256) void agg_einsum(const short* __restrict__ bases,
                                                  const float* __restrict__ wts,
                                                  const int* __restrict__ row_ptr,
                                                  const int* __restrict__ srcs,
                                                  const float* __restrict__ cbias,
                                                  float* __restrict__ outp, int N) {
    __shared__ float agg_lds[4][3][128];
    __shared__ float wts_lds[4][96];
    int wid = threadIdx.x >> 6;
    int lane = threadIdx.x & 63;
    int n = blockIdx.x * 4 + wid;
    if (n >= N) return;  // per-wave uniform; no cross-wave sync used

    int r0 = row_ptr[n];
    int r1 = row_ptr[n + 1];

    // hoist wts load (overlaps with gather loop)
    wts_lds[wid][lane] = wts[(size_t)n * 96 + lane];
    if (lane < 32) wts_lds[wid][64 + lane] = wts[(size_t)n * 96 + 64 + lane];

    const short* bp = bases + 2 * lane;
    const float NI = -3.402823466e+38f;
    float sx0 = 0.f, sy0 = 0.f, sx1 = 0.f, sy1 = 0.f;
    float sx2 = 0.f, sy2 = 0.f, sx3 = 0.f, sy3 = 0.f;
    float mx0 = NI, my0 = NI, mx1 = NI, my1 = NI;
    float mx2 = NI, my2 = NI, mx3 = NI, my3 = NI;

#define GACC(S, SX, SY, MX, MY)                                              \
    {                                                                        \
        unsigned int v = *(const unsigned int*)&bp[(size_t)(S) * 128];       \
        float fx = b2f_lo(v), fy = b2f_hi(v);                                \
        SX += fx; SY += fy; MX = fmaxf(MX, fx); MY = fmaxf(MY, fy);          \
    }

    int r = r0;
    while (r < r1) {
        int chunk = r1 - r;
        if (chunk > 64) chunk = 64;
        int sidx = (lane < chunk) ? srcs[r + lane] : 0;
        int j = 0;
        for (; j + 8 <= chunk; j += 8) {
            int s0 = __shfl(sidx, j + 0), s1 = __shfl(sidx, j + 1);
            int s2 = __shfl(sidx, j + 2), s3 = __shfl(sidx, j + 3);
            int s4 = __shfl(sidx, j + 4), s5 = __shfl(sidx, j + 5);
            int s6 = __shfl(sidx, j + 6), s7 = __shfl(sidx, j + 7);
            GACC(s0, sx0, sy0, mx0, my0);
            GACC(s1, sx1, sy1, mx1, my1);
            GACC(s2, sx2, sy2, mx2, my2);
            GACC(s3, sx3, sy3, mx3, my3);
            GACC(s4, sx0, sy0, mx0, my0);
            GACC(s5, sx1, sy1, mx1, my1);
            GACC(s6, sx2, sy2, mx2, my2);
            GACC(s7, sx3, sy3, mx3, my3);
        }
        for (; j + 4 <= chunk; j += 4) {
            int s0 = __shfl(sidx, j + 0), s1 = __shfl(sidx, j + 1);
            int s2 = __shfl(sidx, j + 2), s3 = __shfl(sidx, j + 3);
            GACC(s0, sx0, sy0, mx0, my0);
            GACC(s1, sx1, sy1, mx1, my1);
            GACC(s2, sx2, sy2, mx2, my2);
            GACC(s3, sx3, sy3, mx3, my3);
        }
        for (; j < chunk; ++j) {
            int s0 = __shfl(sidx, j);
            GACC(s0, sx0, sy0, mx0, my0);
        }
        r += chunk;
    }
#undef GACC

    float sx = (sx0 + sx1) + (sx2 + sx3);
    float sy = (sy0 + sy1) + (sy2 + sy3);
    float mx = fmaxf(fmaxf(mx0, mx1), fmaxf(mx2, mx3));
    float my = fmaxf(fmaxf(my0, my1), fmaxf(my2, my3));
    float inv = 1.0f / (float)(r1 - r0);
    agg_lds[wid][0][2 * lane] = sx;       agg_lds[wid][0][2 * lane + 1] = sy;
    agg_lds[wid][1][2 * lane] = sx * inv; agg_lds[wid][1][2 * lane + 1] = sy * inv;
    agg_lds[wid][2][2 * lane] = mx;       agg_lds[wid][2][2 * lane + 1] = my;

    // wave-level LDS drain: this wave only reads its own slice
    asm volatile("s_waitcnt lgkmcnt(0)" ::: "memory");

#pragma unroll
    for (int j = 0; j < 4; ++j) {
        int o = lane + 64 * j;
        int hh = o >> 5;
        int d = o & 31;
        float acc = cbias[o];
#pragma unroll
        for (int k = 0; k < 12; ++k)
            acc = fmaf(wts_lds[wid][hh * 12 + k], agg_lds[wid][k >> 2][(k & 3) * 32 + d], acc);
        outp[n * 256 + o] = acc;
    }
}

// ---------------- BN (2-stage, deterministic) ----------------
__global__ void bn_stats(const float* __restrict__ v, int N, int C, float* __restrict__ partial) {
    int c = threadIdx.x;  // blockDim == C
    float s = 0.f, s2 = 0.f;
    for (int r = blockIdx.x; r < N; r += gridDim.x) {
        float t = v[r * C + c];
        s += t; s2 += t * t;
    }
    partial[(blockIdx.x * 2 + 0) * C + c] = s;
    partial[(blockIdx.x * 2 + 1) * C + c] = s2;
}

__global__ void bn_finalize(const float* __restrict__ partial, int NB, int C, int N,
                            const float* __restrict__ gamma, const float* __restrict__ beta,
                            float* __restrict__ ss) {
    int c = threadIdx.x;
    if (c >= C) return;
    float s = 0.f, s2 = 0.f;
    for (int b = 0; b < NB; ++b) {
        s += partial[(b * 2 + 0) * C + c];
        s2 += partial[(b * 2 + 1) * C + c];
    }
    float invN = 1.0f / (float)N;
    float mu = s * invN;
    float var = fmaxf(s2 * invN - mu * mu, 0.f);
    float sc = gamma[c] * rsqrtf(var + 1e-5f);
    ss[c] = sc;
    ss[C + c] = beta[c] - mu * sc;
}

// h += relu(out*sc+sh), C=256, vectorized x4; also writes bf16 mirror of h
__global__ void bn_apply_res4(float4* __restrict__ h, const float4* __restrict__ outp,
                              const float* __restrict__ ss, short* __restrict__ hb, int total4) {
    int i = blockIdx.x * blockDim.x + threadIdx.x;
    if (i >= total4) return;
    int c0 = (i * 4) & 255;
    float4 o = outp[i];
    float4 hv = h[i];
    hv.x += fmaxf(o.x * ss[c0 + 0] + ss[256 + c0 + 0], 0.f);
    hv.y += fmaxf(o.y * ss[c0 + 1] + ss[256 + c0 + 1], 0.f);
    hv.z += fmaxf(o.z * ss[c0 + 2] + ss[256 + c0 + 2], 0.f);
    hv.w += fmaxf(o.w * ss[c0 + 3] + ss[256 + c0 + 3], 0.f);
    h[i] = hv;
    short4 hb4;
    hb4.x = f2b(hv.x); hb4.y = f2b(hv.y); hb4.z = f2b(hv.z); hb4.w = f2b(hv.w);
    *(short4*)&hb[(size_t)i * 4] = hb4;
}

// z = relu(z*sc+sh), in place, C power of 2
__global__ void bn_apply(float* __restrict__ z, const float* __restrict__ ss, int total, int C, int Cmask) {
    int i = blockIdx.x * blockDim.x + threadIdx.x;
    if (i >= total) return;
    int c = i & Cmask;
    z[i] = fmaxf(z[i] * ss[c] + ss[C + c], 0.f);
}

// ---------------- Pool ----------------
__device__ int lower_bound_dev(const int* a, int n, int v) {
    int lo = 0, hi = n;
    while (lo < hi) {
        int mid = (lo + hi) >> 1;
        if (a[mid] < v) lo = mid + 1; else hi = mid;
    }
    return lo;
}

__global__ __launch_bounds__(256) void pool_kernel(const float* __restrict__ h,
                                                   const int* __restrict__ batch, int N,
                                                   float* __restrict__ g) {
    __shared__ int sh[2];
    if (threadIdx.x == 0) {
        sh[0] = lower_bound_dev(batch, N, (int)blockIdx.x);
        sh[1] = lower_bound_dev(batch, N, (int)blockIdx.x + 1);
    }
    __syncthreads();
    int s0 = sh[0], s1 = sh[1];
    float s = 0.f;
    for (int r = s0; r < s1; ++r) s += h[r * 256 + threadIdx.x];
    float cnt = (float)(s1 - s0);
    g[blockIdx.x * 256 + threadIdx.x] = s / fmaxf(cnt, 1.0f);
}

// ---------------- MLP ----------------
__global__ void mlp_gemm(const float* __restrict__ in, const float* __restrict__ W,
                         float* __restrict__ outp, int K, int C) {
    extern __shared__ float srow[];
    int r = blockIdx.x;
    for (int k = threadIdx.x; k < K; k += blockDim.x) srow[k] = in[r * K + k];
    __syncthreads();
    int c = threadIdx.x;
    float acc = 0.f;
    for (int k = 0; k < K; ++k) acc = fmaf(srow[k], W[k * C + c], acc);
    outp[r * C + c] = acc;
}

__global__ void final_gemm(const float* __restrict__ z2, const float* __restrict__ w3,
                           const float* __restrict__ b3, float* __restrict__ outp, int G) {
    int g = blockIdx.x * blockDim.x + threadIdx.x;
    if (g >= G) return;
    float acc = b3[0];
    for (int k = 0; k < 64; ++k) acc = fmaf(z2[g * 64 + k], w3[k], acc);
    outp[g] = acc;
}

extern "C" void kernel_launch(void* const* d_in, const int* in_sizes, int n_in,
                              void* d_out, int out_size, void* d_ws, size_t ws_size,
                              hipStream_t stream) {
    const float* atom_emb = (const float*)d_in[0];
    const float* bases_W = (const float*)d_in[1];
    const float* comb_W = (const float*)d_in[2];
    const float* comb_b = (const float*)d_in[3];
    const float* conv_bias = (const float*)d_in[4];
    const float* bn_gamma = (const float*)d_in[5];
    const float* bn_beta = (const float*)d_in[6];
    const float* w1 = (const float*)d_in[7];
    const float* g1 = (const float*)d_in[8];
    const float* b1 = (const float*)d_in[9];
    const float* w2 = (const float*)d_in[10];
    const float* g2 = (const float*)d_in[11];
    const float* b2 = (const float*)d_in[12];
    const float* w3 = (const float*)d_in[13];
    const float* b3 = (const float*)d_in[14];
    const int* x = (const int*)d_in[15];
    const int* edge_index = (const int*)d_in[16];
    const int* batch = (const int*)d_in[17];
    float* out = (float*)d_out;

    const int N = in_sizes[15] / 9;
    const int E = in_sizes[16] / 2;
    const int G = NGRAPH;
    const int NCHUNK = (N + 1023) / 1024;  // scan chunks

    // workspace carve
    char* p = (char*)d_ws;
    auto alloc = [&](size_t bytes) -> void* {
        void* r = (void*)p;
        p += (bytes + 255) & ~(size_t)255;
        return r;
    };
    float* h = (float*)alloc((size_t)N * 256 * 4);
    short* hb = (short*)alloc((size_t)N * 256 * 2);
    float* outb = (float*)alloc((size_t)N * 256 * 4);
    short* bases = (short*)alloc((size_t)N * 128 * 2);
    float* wts = (float*)alloc((size_t)N * 96 * 4);
    short* WT = (short*)alloc((size_t)4 * 224 * 256 * 2);
    int* row_ptr = (int*)alloc((size_t)(N + 1) * 4);
    int* cnt = (int*)alloc((size_t)N * 4);
    int* woff = (int*)alloc((size_t)N * 4);
    int* blksum = (int*)alloc((size_t)256 * 4);
    int* srcs = (int*)alloc((size_t)(E + N) * 4);
    float* partial = (float*)alloc((size_t)256 * 2 * 256 * 4);
    float* ss = (float*)alloc((size_t)2 * 256 * 4);
    float* g = (float*)alloc((size_t)G * 256 * 4);
    float* z1 = (float*)alloc((size_t)G * 128 * 4);
    float* z2 = (float*)alloc((size_t)G * 64 * 4);

    // atom encoder + weight prep
    atom_enc<<<N, 256, 0, stream>>>(x, atom_emb, h, hb, N);
    prep_wt<<<4 * 224, 256, 0, stream>>>(bases_W, comb_W, WT);

    // CSR build
    init_cnt<<<(N + 255) / 256, 256, 0, stream>>>(cnt, N);
    csr_count<<<(E + 255) / 256, 256, 0, stream>>>(edge_index, E, cnt);
    scan_s1<<<NCHUNK, 256, 0, stream>>>(cnt, blksum, N);
    scan_s2<<<1, 256, 0, stream>>>(blksum, NCHUNK, row_ptr, N);
    scan_s3<<<NCHUNK, 256, 0, stream>>>(cnt, blksum, row_ptr, woff, N);
    csr_scatter<<<(E + N + 255) / 256, 256, 0, stream>>>(edge_index, E, N, woff, srcs);

    const int NB = 240;
    for (int l = 0; l < 4; ++l) {
        const short* WTl = WT + (size_t)l * 224 * 256;
        const float* cb = comb_b + (size_t)l * 96;
        const float* cbias = conv_bias + (size_t)l * 256;
        const float* gam = bn_gamma + (size_t)l * 256;
        const float* bet = bn_beta + (size_t)l * 256;

        gemm_mfma<<<(N + 63) / 64, 256, 0, stream>>>(hb, WTl, cb, bases, wts, N);
        agg_einsum<<<(N + 3) / 4, 256, 0, stream>>>(bases, wts, row_ptr, srcs, cbias, outb, N);
        bn_stats<<<NB, 256, 0, stream>>>(outb, N, 256, partial);
        bn_finalize<<<1, 256, 0, stream>>>(partial, NB, 256, N, gam, bet, ss);
        int total4 = N * 256 / 4;
        bn_apply_res4<<<(total4 + 255) / 256, 256, 0, stream>>>((float4*)h, (const float4*)outb, ss, hb, total4);
    }

    // pool
    pool_kernel<<<G, 256, 0, stream>>>(h, batch, N, g);

    // MLP layer 1: 256 -> 128
    mlp_gemm<<<G, 128, 256 * 4, stream>>>(g, w1, z1, 256, 128);
    bn_stats<<<64, 128, 0, stream>>>(z1, G, 128, partial);
    bn_finalize<<<1, 128, 0, stream>>>(partial, 64, 128, G, g1, b1, ss);
    bn_apply<<<(G * 128 + 255) / 256, 256, 0, stream>>>(z1, ss, G * 128, 128, 127);

    // MLP layer 2: 128 -> 64
    mlp_gemm<<<G, 64, 128 * 4, stream>>>(z1, w2, z2, 128, 64);
    bn_stats<<<64, 64, 0, stream>>>(z2, G, 64, partial);
    bn_finalize<<<1, 64, 0, stream>>>(partial, 64, 64, G, g2, b2, ss);
    bn_apply<<<(G * 64 + 255) / 256, 256, 0, stream>>>(z2, ss, G * 64, 64, 63);

    // final: 64 -> 1
    final_gemm<<<(G + 255) / 256, 256, 0, stream>>>(z2, w3, b3, out, G);
}

// Round 5
// 763.676 us; speedup vs baseline: 3.6470x; 1.3566x over previous
//
#include <hip/hip_runtime.h>
#include <hip/hip_bf16.h>

#define HID 256
#define NGRAPH 2048

typedef __attribute__((ext_vector_type(8))) short s16x8;
typedef __attribute__((ext_vector_type(4))) float f32x4v;

__device__ inline short f2b(float f) {
    __hip_bfloat16 b = __float2bfloat16(f);
    return *reinterpret_cast<short*>(&b);
}
__device__ inline float b2f_lo(unsigned int v) {
    return __uint_as_float(v << 16);
}
__device__ inline float b2f_hi(unsigned int v) {
    return __uint_as_float(v & 0xffff0000u);
}

// ---------------- Atom encoder: h fp32 + bf16 mirror ----------------
__global__ __launch_bounds__(256) void atom_enc(const int* __restrict__ x,
                                                const float* __restrict__ emb,
                                                float* __restrict__ h,
                                                short* __restrict__ hb, int N) {
    int n = blockIdx.x;
    int c = threadIdx.x;
    if (n >= N) return;
    const int offs[9] = {0, 119, 124, 136, 148, 158, 164, 170, 172};
    float s = 0.f;
#pragma unroll
    for (int j = 0; j < 9; ++j) {
        int row = x[n * 9 + j] + offs[j];
        s += emb[row * 256 + c];
    }
    h[n * 256 + c] = s;
    hb[n * 256 + c] = f2b(s);
}

// ---------------- Weight prep ----------------
__global__ void prep_wt(const float* __restrict__ bases_W, const float* __restrict__ comb_W,
                        short* __restrict__ WT) {
    int l = blockIdx.x / 224;
    int n = blockIdx.x % 224;
    int k = threadIdx.x;  // 0..255
    float v = (n < 128) ? bases_W[((size_t)l * 256 + k) * 128 + n]
                        : comb_W[((size_t)l * 256 + k) * 96 + (n - 128)];
    WT[((size_t)l * 224 + n) * 256 + k] = f2b(v);
}

// ---------------- CSR build ----------------
__global__ void init_cnt(int* cnt, int N) {
    int i = blockIdx.x * blockDim.x + threadIdx.x;
    if (i < N) cnt[i] = 1;  // self loop
}

__global__ void csr_count(const int* __restrict__ ei, int E, int* cnt) {
    int e = blockIdx.x * blockDim.x + threadIdx.x;
    if (e >= E) return;
    atomicAdd(&cnt[ei[e]], 1);
}

// hierarchical scan: S1 per-1024-chunk sums
__global__ __launch_bounds__(256) void scan_s1(const int* __restrict__ cnt, int* __restrict__ blksum, int N) {
    __shared__ int red[256];
    int base = blockIdx.x * 1024;
    int s = 0;
#pragma unroll
    for (int q = 0; q < 4; ++q) {
        int i = base + threadIdx.x * 4 + q;
        s += (i < N) ? cnt[i] : 0;
    }
    red[threadIdx.x] = s;
    __syncthreads();
    for (int off = 128; off > 0; off >>= 1) {
        if (threadIdx.x < off) red[threadIdx.x] += red[threadIdx.x + off];
        __syncthreads();
    }
    if (threadIdx.x == 0) blksum[blockIdx.x] = red[0];
}

// S2: exclusive scan of block sums (nb <= 256), also writes total to row_ptr[N]
__global__ __launch_bounds__(256) void scan_s2(int* __restrict__ blksum, int nb, int* __restrict__ row_ptr, int N) {
    __shared__ int buf[256];
    int v = (threadIdx.x < nb) ? blksum[threadIdx.x] : 0;
    buf[threadIdx.x] = v;
    __syncthreads();
    for (int off = 1; off < 256; off <<= 1) {
        int t = (threadIdx.x >= off) ? buf[threadIdx.x - off] : 0;
        __syncthreads();
        buf[threadIdx.x] += t;
        __syncthreads();
    }
    if (threadIdx.x < nb) blksum[threadIdx.x] = buf[threadIdx.x] - v;  // exclusive
    if (threadIdx.x == 0) row_ptr[N] = buf[255];
}

// S3: per-chunk local scan + base; writes row_ptr and woff
__global__ __launch_bounds__(256) void scan_s3(const int* __restrict__ cnt, const int* __restrict__ blksum,
                                               int* __restrict__ row_ptr, int* __restrict__ woff, int N) {
    __shared__ int buf[256];
    int base = blockIdx.x * 1024;
    int i0 = base + threadIdx.x * 4;
    int v[4];
    int s = 0;
#pragma unroll
    for (int q = 0; q < 4; ++q) {
        int i = i0 + q;
        v[q] = (i < N) ? cnt[i] : 0;
        s += v[q];
    }
    buf[threadIdx.x] = s;
    __syncthreads();
    for (int off = 1; off < 256; off <<= 1) {
        int t = (threadIdx.x >= off) ? buf[threadIdx.x - off] : 0;
        __syncthreads();
        buf[threadIdx.x] += t;
        __syncthreads();
    }
    int excl = buf[threadIdx.x] - s + blksum[blockIdx.x];
#pragma unroll
    for (int q = 0; q < 4; ++q) {
        int i = i0 + q;
        if (i < N) { row_ptr[i] = excl; woff[i] = excl; }
        excl += v[q];
    }
}

// 4 edges/thread for atomic ILP
__global__ void csr_scatter(const int* __restrict__ ei, int E, int N,
                            int* __restrict__ woff, int* __restrict__ srcs) {
    int i0 = (blockIdx.x * blockDim.x + threadIdx.x) * 4;
    int T = E + N;
    int d[4], s[4], pos[4];
    bool ok[4];
#pragma unroll
    for (int q = 0; q < 4; ++q) {
        int i = i0 + q;
        ok[q] = (i < T);
        if (ok[q]) {
            if (i < E) { d[q] = ei[i]; s[q] = ei[E + i]; }
            else       { d[q] = i - E; s[q] = i - E; }
        }
    }
#pragma unroll
    for (int q = 0; q < 4; ++q)
        if (ok[q]) pos[q] = atomicAdd(&woff[d[q]], 1);
#pragma unroll
    for (int q = 0; q < 4; ++q)
        if (ok[q]) srcs[pos[q]] = s[q];
}

// ---------------- MFMA GEMM: LDS-staged B, double-buffered ----------------
__global__ __launch_bounds__(256) void gemm_mfma(const short* __restrict__ hb,
                                                 const short* __restrict__ WT,
                                                 const float* __restrict__ cb,
                                                 short* __restrict__ bases,
                                                 float* __restrict__ wts, int N) {
    __shared__ short bs[2][32 * 256];  // 2 x 16KB
    int tid = threadIdx.x;
    int wid = tid >> 6;
    int lane = tid & 63;
    int m0 = blockIdx.x * 64 + wid * 16;
    int row_a = m0 + (lane & 15);
    if (row_a > N - 1) row_a = N - 1;
    int kgrp = (lane >> 4) * 8;  // 0,8,16,24

    s16x8 a[8];
#pragma unroll
    for (int i = 0; i < 8; ++i)
        a[i] = *(const s16x8*)&hb[(size_t)row_a * 256 + i * 32 + kgrp];

    int st_col = tid >> 3;
    int st_kk = (tid & 7) * 32;
    int st_sw = (st_col & 7) << 4;
    int st_base = st_col * 512 + st_kk * 2;

    auto stage = [&](int buf, int t) {
        const s16x8* src = (const s16x8*)&WT[(size_t)(t * 32 + st_col) * 256 + st_kk];
        char* dst = (char*)bs[buf];
#pragma unroll
        for (int q = 0; q < 4; ++q)
            *(s16x8*)(dst + ((st_base + q * 16) ^ st_sw)) = src[q];
    };

    stage(0, 0);

    int col = lane & 15;
    int rd_base = col * 512 + (lane >> 4) * 16;
    int rd_sw = (col & 7) << 4;
    int rbase = m0 + (lane >> 4) * 4;

    for (int t = 0; t < 7; ++t) {
        __syncthreads();
        if (t + 1 < 7) stage((t + 1) & 1, t + 1);

        const char* base = (const char*)bs[t & 1];
        f32x4v c0 = {0.f, 0.f, 0.f, 0.f};
        f32x4v c1 = {0.f, 0.f, 0.f, 0.f};
#pragma unroll
        for (int i = 0; i < 8; ++i) {
            s16x8 b0 = *(const s16x8*)(base + ((rd_base + i * 64) ^ rd_sw));
            s16x8 b1 = *(const s16x8*)(base + ((rd_base + 8192 + i * 64) ^ rd_sw));
            c0 = __builtin_amdgcn_mfma_f32_16x16x32_bf16(a[i], b0, c0, 0, 0, 0);
            c1 = __builtin_amdgcn_mfma_f32_16x16x32_bf16(a[i], b1, c1, 0, 0, 0);
        }

        int cc0 = t * 32 + col;
        int cc1 = cc0 + 16;
        float cb0 = (cc0 >= 128) ? cb[cc0 - 128] : 0.f;
        float cb1 = (cc1 >= 128) ? cb[cc1 - 128] : 0.f;
#pragma unroll
        for (int r = 0; r < 4; ++r) {
            int row = rbase + r;
            if (row >= N) continue;
            float v0 = c0[r], v1 = c1[r];
            if (cc0 < 128) bases[(size_t)row * 128 + cc0] = f2b(v0);
            else wts[(size_t)row * 96 + (cc0 - 128)] = v0 + cb0;
            if (cc1 < 128) bases[(size_t)row * 128 + cc1] = f2b(v1);
            else wts[(size_t)row * 96 + (cc1 - 128)] = v1 + cb1;
        }
    }
}

// ---------------- Aggregation v3: shfl-batched srcs, unroll 8, wave-sync ----------------
__global__ __launch_bounds__(256) void agg_einsum(const short* __restrict__ bases,
                                                  const float* __restrict__ wts,
                                                  const int* __restrict__ row_ptr,
                                                  const int* __restrict__ srcs,
                                                  const float* __restrict__ cbias,
                                                  float* __restrict__ outp, int N) {
    __shared__ float agg_lds[4][3][128];
    __shared__ float wts_lds[4][96];
    int wid = threadIdx.x >> 6;
    int lane = threadIdx.x & 63;
    int n = blockIdx.x * 4 + wid;
    if (n >= N) return;  // per-wave uniform; no cross-wave sync used

    int r0 = row_ptr[n];
    int r1 = row_ptr[n + 1];

    // hoist wts load (overlaps with gather loop)
    wts_lds[wid][lane] = wts[(size_t)n * 96 + lane];
    if (lane < 32) wts_lds[wid][64 + lane] = wts[(size_t)n * 96 + 64 + lane];

    const short* bp = bases + 2 * lane;
    const float NI = -3.402823466e+38f;
    float sx0 = 0.f, sy0 = 0.f, sx1 = 0.f, sy1 = 0.f;
    float sx2 = 0.f, sy2 = 0.f, sx3 = 0.f, sy3 = 0.f;
    float mx0 = NI, my0 = NI, mx1 = NI, my1 = NI;
    float mx2 = NI, my2 = NI, mx3 = NI, my3 = NI;

#define GACC(S, SX, SY, MX, MY)                                              \
    {                                                                        \
        unsigned int v = *(const unsigned int*)&bp[(size_t)(S) * 128];       \
        float fx = b2f_lo(v), fy = b2f_hi(v);                                \
        SX += fx; SY += fy; MX = fmaxf(MX, fx); MY = fmaxf(MY, fy);          \
    }

    int r = r0;
    while (r < r1) {
        int chunk = r1 - r;
        if (chunk > 64) chunk = 64;
        int sidx = (lane < chunk) ? srcs[r + lane] : 0;
        int j = 0;
        for (; j + 8 <= chunk; j += 8) {
            int s0 = __shfl(sidx, j + 0), s1 = __shfl(sidx, j + 1);
            int s2 = __shfl(sidx, j + 2), s3 = __shfl(sidx, j + 3);
            int s4 = __shfl(sidx, j + 4), s5 = __shfl(sidx, j + 5);
            int s6 = __shfl(sidx, j + 6), s7 = __shfl(sidx, j + 7);
            GACC(s0, sx0, sy0, mx0, my0);
            GACC(s1, sx1, sy1, mx1, my1);
            GACC(s2, sx2, sy2, mx2, my2);
            GACC(s3, sx3, sy3, mx3, my3);
            GACC(s4, sx0, sy0, mx0, my0);
            GACC(s5, sx1, sy1, mx1, my1);
            GACC(s6, sx2, sy2, mx2, my2);
            GACC(s7, sx3, sy3, mx3, my3);
        }
        for (; j + 4 <= chunk; j += 4) {
            int s0 = __shfl(sidx, j + 0), s1 = __shfl(sidx, j + 1);
            int s2 = __shfl(sidx, j + 2), s3 = __shfl(sidx, j + 3);
            GACC(s0, sx0, sy0, mx0, my0);
            GACC(s1, sx1, sy1, mx1, my1);
            GACC(s2, sx2, sy2, mx2, my2);
            GACC(s3, sx3, sy3, mx3, my3);
        }
        for (; j < chunk; ++j) {
            int s0 = __shfl(sidx, j);
            GACC(s0, sx0, sy0, mx0, my0);
        }
        r += chunk;
    }
#undef GACC

    float sx = (sx0 + sx1) + (sx2 + sx3);
    float sy = (sy0 + sy1) + (sy2 + sy3);
    float mx = fmaxf(fmaxf(mx0, mx1), fmaxf(mx2, mx3));
    float my = fmaxf(fmaxf(my0, my1), fmaxf(my2, my3));
    float inv = 1.0f / (float)(r1 - r0);
    agg_lds[wid][0][2 * lane] = sx;       agg_lds[wid][0][2 * lane + 1] = sy;
    agg_lds[wid][1][2 * lane] = sx * inv; agg_lds[wid][1][2 * lane + 1] = sy * inv;
    agg_lds[wid][2][2 * lane] = mx;       agg_lds[wid][2][2 * lane + 1] = my;

    // wave-level LDS drain: this wave only reads its own slice
    asm volatile("s_waitcnt lgkmcnt(0)" ::: "memory");

#pragma unroll
    for (int j = 0; j < 4; ++j) {
        int o = lane + 64 * j;
        int hh = o >> 5;
        int d = o & 31;
        float acc = cbias[o];
#pragma unroll
        for (int k = 0; k < 12; ++k)
            acc = fmaf(wts_lds[wid][hh * 12 + k], agg_lds[wid][k >> 2][(k & 3) * 32 + d], acc);
        outp[n * 256 + o] = acc;
    }
}

// ---------------- BN (2-stage, deterministic) ----------------
__global__ void bn_stats(const float* __restrict__ v, int N, int C, float* __restrict__ partial) {
    int c = threadIdx.x;  // blockDim == C
    float s = 0.f, s2 = 0.f;
    for (int r = blockIdx.x; r < N; r += gridDim.x) {
        float t = v[r * C + c];
        s += t; s2 += t * t;
    }
    partial[(blockIdx.x * 2 + 0) * C + c] = s;
    partial[(blockIdx.x * 2 + 1) * C + c] = s2;
}

// parallel finalize: one block per channel
__global__ __launch_bounds__(256) void bn_finalize(const float* __restrict__ partial, int NB, int C, int N,
                                                   const float* __restrict__ gamma, const float* __restrict__ beta,
                                                   float* __restrict__ ss) {
    int c = blockIdx.x;
    float s = 0.f, s2 = 0.f;
    for (int b = threadIdx.x; b < NB; b += 256) {
        s += partial[(b * 2 + 0) * C + c];
        s2 += partial[(b * 2 + 1) * C + c];
    }
#pragma unroll
    for (int off = 32; off > 0; off >>= 1) {
        s += __shfl_down(s, off);
        s2 += __shfl_down(s2, off);
    }
    __shared__ float wsum[4][2];
    int wid = threadIdx.x >> 6;
    int lane = threadIdx.x & 63;
    if (lane == 0) { wsum[wid][0] = s; wsum[wid][1] = s2; }
    __syncthreads();
    if (threadIdx.x == 0) {
        s = (wsum[0][0] + wsum[1][0]) + (wsum[2][0] + wsum[3][0]);
        s2 = (wsum[0][1] + wsum[1][1]) + (wsum[2][1] + wsum[3][1]);
        float invN = 1.0f / (float)N;
        float mu = s * invN;
        float var = fmaxf(s2 * invN - mu * mu, 0.f);
        float sc = gamma[c] * rsqrtf(var + 1e-5f);
        ss[c] = sc;
        ss[C + c] = beta[c] - mu * sc;
    }
}

// h += relu(out*sc+sh), C=256, vectorized x4; also writes bf16 mirror of h
__global__ void bn_apply_res4(float4* __restrict__ h, const float4* __restrict__ outp,
                              const float* __restrict__ ss, short* __restrict__ hb, int total4) {
    int i = blockIdx.x * blockDim.x + threadIdx.x;
    if (i >= total4) return;
    int c0 = (i * 4) & 255;
    float4 o = outp[i];
    float4 hv = h[i];
    hv.x += fmaxf(o.x * ss[c0 + 0] + ss[256 + c0 + 0], 0.f);
    hv.y += fmaxf(o.y * ss[c0 + 1] + ss[256 + c0 + 1], 0.f);
    hv.z += fmaxf(o.z * ss[c0 + 2] + ss[256 + c0 + 2], 0.f);
    hv.w += fmaxf(o.w * ss[c0 + 3] + ss[256 + c0 + 3], 0.f);
    h[i] = hv;
    short4 hb4;
    hb4.x = f2b(hv.x); hb4.y = f2b(hv.y); hb4.z = f2b(hv.z); hb4.w = f2b(hv.w);
    *(short4*)&hb[(size_t)i * 4] = hb4;
}

// z = relu(z*sc+sh), in place, C power of 2
__global__ void bn_apply(float* __restrict__ z, const float* __restrict__ ss, int total, int C, int Cmask) {
    int i = blockIdx.x * blockDim.x + threadIdx.x;
    if (i >= total) return;
    int c = i & Cmask;
    z[i] = fmaxf(z[i] * ss[c] + ss[C + c], 0.f);
}

// ---------------- Pool ----------------
__device__ int lower_bound_dev(const int* a, int n, int v) {
    int lo = 0, hi = n;
    while (lo < hi) {
        int mid = (lo + hi) >> 1;
        if (a[mid] < v) lo = mid + 1; else hi = mid;
    }
    return lo;
}

__global__ __launch_bounds__(256) void pool_kernel(const float* __restrict__ h,
                                                   const int* __restrict__ batch, int N,
                                                   float* __restrict__ g) {
    __shared__ int sh[2];
    if (threadIdx.x == 0) {
        sh[0] = lower_bound_dev(batch, N, (int)blockIdx.x);
        sh[1] = lower_bound_dev(batch, N, (int)blockIdx.x + 1);
    }
    __syncthreads();
    int s0 = sh[0], s1 = sh[1];
    float s = 0.f;
    for (int r = s0; r < s1; ++r) s += h[r * 256 + threadIdx.x];
    float cnt = (float)(s1 - s0);
    g[blockIdx.x * 256 + threadIdx.x] = s / fmaxf(cnt, 1.0f);
}

// ---------------- MLP ----------------
__global__ void mlp_gemm(const float* __restrict__ in, const float* __restrict__ W,
                         float* __restrict__ outp, int K, int C) {
    extern __shared__ float srow[];
    int r = blockIdx.x;
    for (int k = threadIdx.x; k < K; k += blockDim.x) srow[k] = in[r * K + k];
    __syncthreads();
    int c = threadIdx.x;
    float acc = 0.f;
    for (int k = 0; k < K; ++k) acc = fmaf(srow[k], W[k * C + c], acc);
    outp[r * C + c] = acc;
}

__global__ void final_gemm(const float* __restrict__ z2, const float* __restrict__ w3,
                           const float* __restrict__ b3, float* __restrict__ outp, int G) {
    int g = blockIdx.x * blockDim.x + threadIdx.x;
    if (g >= G) return;
    float acc = b3[0];
    for (int k = 0; k < 64; ++k) acc = fmaf(z2[g * 64 + k], w3[k], acc);
    outp[g] = acc;
}

extern "C" void kernel_launch(void* const* d_in, const int* in_sizes, int n_in,
                              void* d_out, int out_size, void* d_ws, size_t ws_size,
                              hipStream_t stream) {
    const float* atom_emb = (const float*)d_in[0];
    const float* bases_W = (const float*)d_in[1];
    const float* comb_W = (const float*)d_in[2];
    const float* comb_b = (const float*)d_in[3];
    const float* conv_bias = (const float*)d_in[4];
    const float* bn_gamma = (const float*)d_in[5];
    const float* bn_beta = (const float*)d_in[6];
    const float* w1 = (const float*)d_in[7];
    const float* g1 = (const float*)d_in[8];
    const float* b1 = (const float*)d_in[9];
    const float* w2 = (const float*)d_in[10];
    const float* g2 = (const float*)d_in[11];
    const float* b2 = (const float*)d_in[12];
    const float* w3 = (const float*)d_in[13];
    const float* b3 = (const float*)d_in[14];
    const int* x = (const int*)d_in[15];
    const int* edge_index = (const int*)d_in[16];
    const int* batch = (const int*)d_in[17];
    float* out = (float*)d_out;

    const int N = in_sizes[15] / 9;
    const int E = in_sizes[16] / 2;
    const int G = NGRAPH;
    const int NCHUNK = (N + 1023) / 1024;  // scan chunks

    // workspace carve
    char* p = (char*)d_ws;
    auto alloc = [&](size_t bytes) -> void* {
        void* r = (void*)p;
        p += (bytes + 255) & ~(size_t)255;
        return r;
    };
    float* h = (float*)alloc((size_t)N * 256 * 4);
    short* hb = (short*)alloc((size_t)N * 256 * 2);
    float* outb = (float*)alloc((size_t)N * 256 * 4);
    short* bases = (short*)alloc((size_t)N * 128 * 2);
    float* wts = (float*)alloc((size_t)N * 96 * 4);
    short* WT = (short*)alloc((size_t)4 * 224 * 256 * 2);
    int* row_ptr = (int*)alloc((size_t)(N + 1) * 4);
    int* cnt = (int*)alloc((size_t)N * 4);
    int* woff = (int*)alloc((size_t)N * 4);
    int* blksum = (int*)alloc((size_t)256 * 4);
    int* srcs = (int*)alloc((size_t)(E + N) * 4);
    float* partial = (float*)alloc((size_t)256 * 2 * 256 * 4);
    float* ss = (float*)alloc((size_t)2 * 256 * 4);
    float* g = (float*)alloc((size_t)G * 256 * 4);
    float* z1 = (float*)alloc((size_t)G * 128 * 4);
    float* z2 = (float*)alloc((size_t)G * 64 * 4);

    // atom encoder + weight prep
    atom_enc<<<N, 256, 0, stream>>>(x, atom_emb, h, hb, N);
    prep_wt<<<4 * 224, 256, 0, stream>>>(bases_W, comb_W, WT);

    // CSR build
    init_cnt<<<(N + 255) / 256, 256, 0, stream>>>(cnt, N);
    csr_count<<<(E + 255) / 256, 256, 0, stream>>>(edge_index, E, cnt);
    scan_s1<<<NCHUNK, 256, 0, stream>>>(cnt, blksum, N);
    scan_s2<<<1, 256, 0, stream>>>(blksum, NCHUNK, row_ptr, N);
    scan_s3<<<NCHUNK, 256, 0, stream>>>(cnt, blksum, row_ptr, woff, N);
    csr_scatter<<<(E + N + 1023) / 1024, 256, 0, stream>>>(edge_index, E, N, woff, srcs);

    const int NB = 240;
    for (int l = 0; l < 4; ++l) {
        const short* WTl = WT + (size_t)l * 224 * 256;
        const float* cb = comb_b + (size_t)l * 96;
        const float* cbias = conv_bias + (size_t)l * 256;
        const float* gam = bn_gamma + (size_t)l * 256;
        const float* bet = bn_beta + (size_t)l * 256;

        gemm_mfma<<<(N + 63) / 64, 256, 0, stream>>>(hb, WTl, cb, bases, wts, N);
        agg_einsum<<<(N + 3) / 4, 256, 0, stream>>>(bases, wts, row_ptr, srcs, cbias, outb, N);
        bn_stats<<<NB, 256, 0, stream>>>(outb, N, 256, partial);
        bn_finalize<<<256, 256, 0, stream>>>(partial, NB, 256, N, gam, bet, ss);
        int total4 = N * 256 / 4;
        bn_apply_res4<<<(total4 + 255) / 256, 256, 0, stream>>>((float4*)h, (const float4*)outb, ss, hb, total4);
    }

    // pool
    pool_kernel<<<G, 256, 0, stream>>>(h, batch, N, g);

    // MLP layer 1: 256 -> 128
    mlp_gemm<<<G, 128, 256 * 4, stream>>>(g, w1, z1, 256, 128);
    bn_stats<<<64, 128, 0, stream>>>(z1, G, 128, partial);
    bn_finalize<<<128, 256, 0, stream>>>(partial, 64, 128, G, g1, b1, ss);
    bn_apply<<<(G * 128 + 255) / 256, 256, 0, stream>>>(z1, ss, G * 128, 128, 127);

    // MLP layer 2: 128 -> 64
    mlp_gemm<<<G, 64, 128 * 4, stream>>>(z1, w2, z2, 128, 64);
    bn_stats<<<64, 64, 0, stream>>>(z2, G, 64, partial);
    bn_finalize<<<64, 256, 0, stream>>>(partial, 64, 64, G, g2, b2, ss);
    bn_apply<<<(G * 64 + 255) / 256, 256, 0, stream>>>(z2, ss, G * 64, 64, 63);

    // final: 64 -> 1
    final_gemm<<<(G + 255) / 256, 256, 0, stream>>>(z2, w3, b3, out, G);
}

// Round 6
// 599.815 us; speedup vs baseline: 4.6433x; 1.2732x over previous
//
#include <hip/hip_runtime.h>
#include <hip/hip_bf16.h>

#define HID 256
#define NGRAPH 2048
#define SNB 768  // bn_stats256 grid

typedef __attribute__((ext_vector_type(8))) short s16x8;
typedef __attribute__((ext_vector_type(4))) float f32x4v;

__device__ inline short f2b(float f) {
    __hip_bfloat16 b = __float2bfloat16(f);
    return *reinterpret_cast<short*>(&b);
}
__device__ inline float b2f_lo(unsigned int v) {
    return __uint_as_float(v << 16);
}
__device__ inline float b2f_hi(unsigned int v) {
    return __uint_as_float(v & 0xffff0000u);
}

// ---------------- Atom encoder: h fp32 + bf16 mirror ----------------
__global__ __launch_bounds__(256) void atom_enc(const int* __restrict__ x,
                                                const float* __restrict__ emb,
                                                float* __restrict__ h,
                                                short* __restrict__ hb, int N) {
    int n = blockIdx.x;
    int c = threadIdx.x;
    if (n >= N) return;
    const int offs[9] = {0, 119, 124, 136, 148, 158, 164, 170, 172};
    float s = 0.f;
#pragma unroll
    for (int j = 0; j < 9; ++j) {
        int row = x[n * 9 + j] + offs[j];
        s += emb[row * 256 + c];
    }
    h[n * 256 + c] = s;
    hb[n * 256 + c] = f2b(s);
}

// ---------------- Weight prep ----------------
__global__ void prep_wt(const float* __restrict__ bases_W, const float* __restrict__ comb_W,
                        short* __restrict__ WT) {
    int l = blockIdx.x / 224;
    int n = blockIdx.x % 224;
    int k = threadIdx.x;  // 0..255
    float v = (n < 128) ? bases_W[((size_t)l * 256 + k) * 128 + n]
                        : comb_W[((size_t)l * 256 + k) * 96 + (n - 128)];
    WT[((size_t)l * 224 + n) * 256 + k] = f2b(v);
}

// ---------------- CSR build ----------------
__global__ void init_cnt(int* cnt, int N) {
    int i = blockIdx.x * blockDim.x + threadIdx.x;
    if (i < N) cnt[i] = 1;  // self loop
}

__global__ void csr_count(const int* __restrict__ ei, int E, int* cnt) {
    int e = blockIdx.x * blockDim.x + threadIdx.x;
    if (e >= E) return;
    atomicAdd(&cnt[ei[e]], 1);
}

// hierarchical scan: S1 per-1024-chunk sums
__global__ __launch_bounds__(256) void scan_s1(const int* __restrict__ cnt, int* __restrict__ blksum, int N) {
    __shared__ int red[256];
    int base = blockIdx.x * 1024;
    int s = 0;
#pragma unroll
    for (int q = 0; q < 4; ++q) {
        int i = base + threadIdx.x * 4 + q;
        s += (i < N) ? cnt[i] : 0;
    }
    red[threadIdx.x] = s;
    __syncthreads();
    for (int off = 128; off > 0; off >>= 1) {
        if (threadIdx.x < off) red[threadIdx.x] += red[threadIdx.x + off];
        __syncthreads();
    }
    if (threadIdx.x == 0) blksum[blockIdx.x] = red[0];
}

// S2: exclusive scan of block sums (nb <= 256), also writes total to row_ptr[N]
__global__ __launch_bounds__(256) void scan_s2(int* __restrict__ blksum, int nb, int* __restrict__ row_ptr, int N) {
    __shared__ int buf[256];
    int v = (threadIdx.x < nb) ? blksum[threadIdx.x] : 0;
    buf[threadIdx.x] = v;
    __syncthreads();
    for (int off = 1; off < 256; off <<= 1) {
        int t = (threadIdx.x >= off) ? buf[threadIdx.x - off] : 0;
        __syncthreads();
        buf[threadIdx.x] += t;
        __syncthreads();
    }
    if (threadIdx.x < nb) blksum[threadIdx.x] = buf[threadIdx.x] - v;  // exclusive
    if (threadIdx.x == 0) row_ptr[N] = buf[255];
}

// S3: per-chunk local scan + base; writes row_ptr and woff
__global__ __launch_bounds__(256) void scan_s3(const int* __restrict__ cnt, const int* __restrict__ blksum,
                                               int* __restrict__ row_ptr, int* __restrict__ woff, int N) {
    __shared__ int buf[256];
    int base = blockIdx.x * 1024;
    int i0 = base + threadIdx.x * 4;
    int v[4];
    int s = 0;
#pragma unroll
    for (int q = 0; q < 4; ++q) {
        int i = i0 + q;
        v[q] = (i < N) ? cnt[i] : 0;
        s += v[q];
    }
    buf[threadIdx.x] = s;
    __syncthreads();
    for (int off = 1; off < 256; off <<= 1) {
        int t = (threadIdx.x >= off) ? buf[threadIdx.x - off] : 0;
        __syncthreads();
        buf[threadIdx.x] += t;
        __syncthreads();
    }
    int excl = buf[threadIdx.x] - s + blksum[blockIdx.x];
#pragma unroll
    for (int q = 0; q < 4; ++q) {
        int i = i0 + q;
        if (i < N) { row_ptr[i] = excl; woff[i] = excl; }
        excl += v[q];
    }
}

// 4 edges/thread for atomic ILP
__global__ void csr_scatter(const int* __restrict__ ei, int E, int N,
                            int* __restrict__ woff, int* __restrict__ srcs) {
    int i0 = (blockIdx.x * blockDim.x + threadIdx.x) * 4;
    int T = E + N;
    int d[4], s[4], pos[4];
    bool ok[4];
#pragma unroll
    for (int q = 0; q < 4; ++q) {
        int i = i0 + q;
        ok[q] = (i < T);
        if (ok[q]) {
            if (i < E) { d[q] = ei[i]; s[q] = ei[E + i]; }
            else       { d[q] = i - E; s[q] = i - E; }
        }
    }
#pragma unroll
    for (int q = 0; q < 4; ++q)
        if (ok[q]) pos[q] = atomicAdd(&woff[d[q]], 1);
#pragma unroll
    for (int q = 0; q < 4; ++q)
        if (ok[q]) srcs[pos[q]] = s[q];
}

// ---------------- MFMA GEMM: LDS-staged B, double-buffered ----------------
__global__ __launch_bounds__(256) void gemm_mfma(const short* __restrict__ hb,
                                                 const short* __restrict__ WT,
                                                 const float* __restrict__ cb,
                                                 short* __restrict__ bases,
                                                 float* __restrict__ wts, int N) {
    __shared__ short bs[2][32 * 256];  // 2 x 16KB
    int tid = threadIdx.x;
    int wid = tid >> 6;
    int lane = tid & 63;
    int m0 = blockIdx.x * 64 + wid * 16;
    int row_a = m0 + (lane & 15);
    if (row_a > N - 1) row_a = N - 1;
    int kgrp = (lane >> 4) * 8;  // 0,8,16,24

    s16x8 a[8];
#pragma unroll
    for (int i = 0; i < 8; ++i)
        a[i] = *(const s16x8*)&hb[(size_t)row_a * 256 + i * 32 + kgrp];

    int st_col = tid >> 3;
    int st_kk = (tid & 7) * 32;
    int st_sw = (st_col & 7) << 4;
    int st_base = st_col * 512 + st_kk * 2;

    auto stage = [&](int buf, int t) {
        const s16x8* src = (const s16x8*)&WT[(size_t)(t * 32 + st_col) * 256 + st_kk];
        char* dst = (char*)bs[buf];
#pragma unroll
        for (int q = 0; q < 4; ++q)
            *(s16x8*)(dst + ((st_base + q * 16) ^ st_sw)) = src[q];
    };

    stage(0, 0);

    int col = lane & 15;
    int rd_base = col * 512 + (lane >> 4) * 16;
    int rd_sw = (col & 7) << 4;
    int rbase = m0 + (lane >> 4) * 4;

    for (int t = 0; t < 7; ++t) {
        __syncthreads();
        if (t + 1 < 7) stage((t + 1) & 1, t + 1);

        const char* base = (const char*)bs[t & 1];
        f32x4v c0 = {0.f, 0.f, 0.f, 0.f};
        f32x4v c1 = {0.f, 0.f, 0.f, 0.f};
#pragma unroll
        for (int i = 0; i < 8; ++i) {
            s16x8 b0 = *(const s16x8*)(base + ((rd_base + i * 64) ^ rd_sw));
            s16x8 b1 = *(const s16x8*)(base + ((rd_base + 8192 + i * 64) ^ rd_sw));
            c0 = __builtin_amdgcn_mfma_f32_16x16x32_bf16(a[i], b0, c0, 0, 0, 0);
            c1 = __builtin_amdgcn_mfma_f32_16x16x32_bf16(a[i], b1, c1, 0, 0, 0);
        }

        int cc0 = t * 32 + col;
        int cc1 = cc0 + 16;
        float cb0 = (cc0 >= 128) ? cb[cc0 - 128] : 0.f;
        float cb1 = (cc1 >= 128) ? cb[cc1 - 128] : 0.f;
#pragma unroll
        for (int r = 0; r < 4; ++r) {
            int row = rbase + r;
            if (row >= N) continue;
            float v0 = c0[r], v1 = c1[r];
            if (cc0 < 128) bases[(size_t)row * 128 + cc0] = f2b(v0);
            else wts[(size_t)row * 96 + (cc0 - 128)] = v0 + cb0;
            if (cc1 < 128) bases[(size_t)row * 128 + cc1] = f2b(v1);
            else wts[(size_t)row * 96 + (cc1 - 128)] = v1 + cb1;
        }
    }
}

// ---------------- Aggregation v4: 8B gathers, edge pairs across wave halves ----------------
__global__ __launch_bounds__(256) void agg_einsum(const short* __restrict__ bases,
                                                  const float* __restrict__ wts,
                                                  const int* __restrict__ row_ptr,
                                                  const int* __restrict__ srcs,
                                                  const float* __restrict__ cbias,
                                                  float* __restrict__ outp, int N) {
    __shared__ float agg_lds[4][3][128];
    __shared__ float wts_lds[4][96];
    int wid = threadIdx.x >> 6;
    int lane = threadIdx.x & 63;
    int n = blockIdx.x * 4 + wid;
    if (n >= N) return;  // per-wave uniform; no cross-wave sync used

    int r0 = row_ptr[n];
    int r1 = row_ptr[n + 1];

    // hoist wts load (overlaps with gather loop)
    wts_lds[wid][lane] = wts[(size_t)n * 96 + lane];
    if (lane < 32) wts_lds[wid][64 + lane] = wts[(size_t)n * 96 + 64 + lane];

    int g = lane & 31;   // channel group: bf16 channels 4g..4g+3
    int half = lane >> 5;  // which edge of each pair
    const short* bp = bases + 4 * g;
    const float NI = -3.402823466e+38f;
    float sA0 = 0.f, sA1 = 0.f, sA2 = 0.f, sA3 = 0.f;
    float sB0 = 0.f, sB1 = 0.f, sB2 = 0.f, sB3 = 0.f;
    float mA0 = NI, mA1 = NI, mA2 = NI, mA3 = NI;
    float mB0 = NI, mB1 = NI, mB2 = NI, mB3 = NI;

#define GACC8(S, s0_, s1_, s2_, s3_, m0_, m1_, m2_, m3_)                     \
    {                                                                        \
        uint2 v = *(const uint2*)&bp[(size_t)(S) * 128];                     \
        float f0 = b2f_lo(v.x), f1 = b2f_hi(v.x);                            \
        float f2 = b2f_lo(v.y), f3 = b2f_hi(v.y);                            \
        s0_ += f0; s1_ += f1; s2_ += f2; s3_ += f3;                          \
        m0_ = fmaxf(m0_, f0); m1_ = fmaxf(m1_, f1);                          \
        m2_ = fmaxf(m2_, f2); m3_ = fmaxf(m3_, f3);                          \
    }

    int r = r0;
    while (r < r1) {
        int chunk = r1 - r;
        if (chunk > 64) chunk = 64;
        int sidx = (lane < chunk) ? srcs[r + lane] : 0;
        int npair = chunk >> 1;
        int jp = 0;
        for (; jp + 4 <= npair; jp += 4) {
            int e0 = (jp + 0) * 2 + half, e1 = (jp + 1) * 2 + half;
            int e2 = (jp + 2) * 2 + half, e3 = (jp + 3) * 2 + half;
            int s0 = __shfl(sidx, e0), s1 = __shfl(sidx, e1);
            int s2 = __shfl(sidx, e2), s3 = __shfl(sidx, e3);
            GACC8(s0, sA0, sA1, sA2, sA3, mA0, mA1, mA2, mA3);
            GACC8(s1, sB0, sB1, sB2, sB3, mB0, mB1, mB2, mB3);
            GACC8(s2, sA0, sA1, sA2, sA3, mA0, mA1, mA2, mA3);
            GACC8(s3, sB0, sB1, sB2, sB3, mB0, mB1, mB2, mB3);
        }
        for (; jp < npair; ++jp) {
            int e0 = jp * 2 + half;
            int s0 = __shfl(sidx, e0);
            GACC8(s0, sA0, sA1, sA2, sA3, mA0, mA1, mA2, mA3);
        }
        if (chunk & 1) {
            int s0 = __shfl(sidx, chunk - 1);
            if (half == 0) {
                GACC8(s0, sB0, sB1, sB2, sB3, mB0, mB1, mB2, mB3);
            }
        }
        r += chunk;
    }
#undef GACC8

    // merge A/B sets
    float s0 = sA0 + sB0, s1 = sA1 + sB1, s2 = sA2 + sB2, s3 = sA3 + sB3;
    float m0 = fmaxf(mA0, mB0), m1 = fmaxf(mA1, mB1);
    float m2 = fmaxf(mA2, mB2), m3 = fmaxf(mA3, mB3);
    // merge halves (lane l <-> l^32)
    s0 += __shfl_xor(s0, 32); s1 += __shfl_xor(s1, 32);
    s2 += __shfl_xor(s2, 32); s3 += __shfl_xor(s3, 32);
    m0 = fmaxf(m0, __shfl_xor(m0, 32)); m1 = fmaxf(m1, __shfl_xor(m1, 32));
    m2 = fmaxf(m2, __shfl_xor(m2, 32)); m3 = fmaxf(m3, __shfl_xor(m3, 32));

    float inv = 1.0f / (float)(r1 - r0);
    if (half == 0) {
        float4 sv = make_float4(s0, s1, s2, s3);
        float4 mv = make_float4(s0 * inv, s1 * inv, s2 * inv, s3 * inv);
        float4 xv = make_float4(m0, m1, m2, m3);
        *(float4*)&agg_lds[wid][0][4 * g] = sv;
        *(float4*)&agg_lds[wid][1][4 * g] = mv;
        *(float4*)&agg_lds[wid][2][4 * g] = xv;
    }

    // wave-level LDS drain: this wave only reads its own slice
    asm volatile("s_waitcnt lgkmcnt(0)" ::: "memory");

#pragma unroll
    for (int j = 0; j < 4; ++j) {
        int o = lane + 64 * j;
        int hh = o >> 5;
        int d = o & 31;
        float acc = cbias[o];
#pragma unroll
        for (int k = 0; k < 12; ++k)
            acc = fmaf(wts_lds[wid][hh * 12 + k], agg_lds[wid][k >> 2][(k & 3) * 32 + d], acc);
        outp[n * 256 + o] = acc;
    }
}

// ---------------- BN stats v2 (C=256): float4 loads, 4 waves, LDS reduce ----------------
__global__ __launch_bounds__(256) void bn_stats256(const float4* __restrict__ v, int N,
                                                   float* __restrict__ partial) {
    __shared__ float red[4][2][256];
    int wid = threadIdx.x >> 6;
    int lane = threadIdx.x & 63;
    float4 s = {0.f, 0.f, 0.f, 0.f}, s2 = {0.f, 0.f, 0.f, 0.f};
    int nb = gridDim.x;
    for (int r = blockIdx.x * 8 + wid * 2; r < N; r += nb * 8) {
        float4 t0 = v[(size_t)r * 64 + lane];
        int r1 = r + 1;
        if (r1 < N) {
            float4 t1 = v[(size_t)r1 * 64 + lane];
            s.x += t1.x; s.y += t1.y; s.z += t1.z; s.w += t1.w;
            s2.x += t1.x * t1.x; s2.y += t1.y * t1.y; s2.z += t1.z * t1.z; s2.w += t1.w * t1.w;
        }
        s.x += t0.x; s.y += t0.y; s.z += t0.z; s.w += t0.w;
        s2.x += t0.x * t0.x; s2.y += t0.y * t0.y; s2.z += t0.z * t0.z; s2.w += t0.w * t0.w;
    }
    *(float4*)&red[wid][0][lane * 4] = s;
    *(float4*)&red[wid][1][lane * 4] = s2;
    __syncthreads();
    int c = threadIdx.x;
    float ps = (red[0][0][c] + red[1][0][c]) + (red[2][0][c] + red[3][0][c]);
    float ps2 = (red[0][1][c] + red[1][1][c]) + (red[2][1][c] + red[3][1][c]);
    partial[(blockIdx.x * 2 + 0) * 256 + c] = ps;
    partial[(blockIdx.x * 2 + 1) * 256 + c] = ps2;
}

// ---------------- BN stats (generic, small inputs) ----------------
__global__ void bn_stats(const float* __restrict__ v, int N, int C, float* __restrict__ partial) {
    int c = threadIdx.x;  // blockDim == C
    float s = 0.f, s2 = 0.f;
    for (int r = blockIdx.x; r < N; r += gridDim.x) {
        float t = v[r * C + c];
        s += t; s2 += t * t;
    }
    partial[(blockIdx.x * 2 + 0) * C + c] = s;
    partial[(blockIdx.x * 2 + 1) * C + c] = s2;
}

// parallel finalize: one block per channel
__global__ __launch_bounds__(256) void bn_finalize(const float* __restrict__ partial, int NB, int C, int N,
                                                   const float* __restrict__ gamma, const float* __restrict__ beta,
                                                   float* __restrict__ ss) {
    int c = blockIdx.x;
    float s = 0.f, s2 = 0.f;
    for (int b = threadIdx.x; b < NB; b += 256) {
        s += partial[(b * 2 + 0) * C + c];
        s2 += partial[(b * 2 + 1) * C + c];
    }
#pragma unroll
    for (int off = 32; off > 0; off >>= 1) {
        s += __shfl_down(s, off);
        s2 += __shfl_down(s2, off);
    }
    __shared__ float wsum[4][2];
    int wid = threadIdx.x >> 6;
    int lane = threadIdx.x & 63;
    if (lane == 0) { wsum[wid][0] = s; wsum[wid][1] = s2; }
    __syncthreads();
    if (threadIdx.x == 0) {
        s = (wsum[0][0] + wsum[1][0]) + (wsum[2][0] + wsum[3][0]);
        s2 = (wsum[0][1] + wsum[1][1]) + (wsum[2][1] + wsum[3][1]);
        float invN = 1.0f / (float)N;
        float mu = s * invN;
        float var = fmaxf(s2 * invN - mu * mu, 0.f);
        float sc = gamma[c] * rsqrtf(var + 1e-5f);
        ss[c] = sc;
        ss[C + c] = beta[c] - mu * sc;
    }
}

// h += relu(out*sc+sh), C=256, vectorized x4; also writes bf16 mirror of h
__global__ void bn_apply_res4(float4* __restrict__ h, const float4* __restrict__ outp,
                              const float* __restrict__ ss, short* __restrict__ hb, int total4) {
    int i = blockIdx.x * blockDim.x + threadIdx.x;
    if (i >= total4) return;
    int c0 = (i * 4) & 255;
    float4 o = outp[i];
    float4 hv = h[i];
    hv.x += fmaxf(o.x * ss[c0 + 0] + ss[256 + c0 + 0], 0.f);
    hv.y += fmaxf(o.y * ss[c0 + 1] + ss[256 + c0 + 1], 0.f);
    hv.z += fmaxf(o.z * ss[c0 + 2] + ss[256 + c0 + 2], 0.f);
    hv.w += fmaxf(o.w * ss[c0 + 3] + ss[256 + c0 + 3], 0.f);
    h[i] = hv;
    short4 hb4;
    hb4.x = f2b(hv.x); hb4.y = f2b(hv.y); hb4.z = f2b(hv.z); hb4.w = f2b(hv.w);
    *(short4*)&hb[(size_t)i * 4] = hb4;
}

// z = relu(z*sc+sh), in place, C power of 2
__global__ void bn_apply(float* __restrict__ z, const float* __restrict__ ss, int total, int C, int Cmask) {
    int i = blockIdx.x * blockDim.x + threadIdx.x;
    if (i >= total) return;
    int c = i & Cmask;
    z[i] = fmaxf(z[i] * ss[c] + ss[C + c], 0.f);
}

// ---------------- Pool ----------------
__device__ int lower_bound_dev(const int* a, int n, int v) {
    int lo = 0, hi = n;
    while (lo < hi) {
        int mid = (lo + hi) >> 1;
        if (a[mid] < v) lo = mid + 1; else hi = mid;
    }
    return lo;
}

__global__ __launch_bounds__(256) void pool_kernel(const float* __restrict__ h,
                                                   const int* __restrict__ batch, int N,
                                                   float* __restrict__ g) {
    __shared__ int sh[2];
    if (threadIdx.x == 0) {
        sh[0] = lower_bound_dev(batch, N, (int)blockIdx.x);
        sh[1] = lower_bound_dev(batch, N, (int)blockIdx.x + 1);
    }
    __syncthreads();
    int s0 = sh[0], s1 = sh[1];
    float s = 0.f;
    for (int r = s0; r < s1; ++r) s += h[r * 256 + threadIdx.x];
    float cnt = (float)(s1 - s0);
    g[blockIdx.x * 256 + threadIdx.x] = s / fmaxf(cnt, 1.0f);
}

// ---------------- MLP ----------------
__global__ void mlp_gemm(const float* __restrict__ in, const float* __restrict__ W,
                         float* __restrict__ outp, int K, int C) {
    extern __shared__ float srow[];
    int r = blockIdx.x;
    for (int k = threadIdx.x; k < K; k += blockDim.x) srow[k] = in[r * K + k];
    __syncthreads();
    int c = threadIdx.x;
    float acc = 0.f;
    for (int k = 0; k < K; ++k) acc = fmaf(srow[k], W[k * C + c], acc);
    outp[r * C + c] = acc;
}

__global__ void final_gemm(const float* __restrict__ z2, const float* __restrict__ w3,
                           const float* __restrict__ b3, float* __restrict__ outp, int G) {
    int g = blockIdx.x * blockDim.x + threadIdx.x;
    if (g >= G) return;
    float acc = b3[0];
    for (int k = 0; k < 64; ++k) acc = fmaf(z2[g * 64 + k], w3[k], acc);
    outp[g] = acc;
}

extern "C" void kernel_launch(void* const* d_in, const int* in_sizes, int n_in,
                              void* d_out, int out_size, void* d_ws, size_t ws_size,
                              hipStream_t stream) {
    const float* atom_emb = (const float*)d_in[0];
    const float* bases_W = (const float*)d_in[1];
    const float* comb_W = (const float*)d_in[2];
    const float* comb_b = (const float*)d_in[3];
    const float* conv_bias = (const float*)d_in[4];
    const float* bn_gamma = (const float*)d_in[5];
    const float* bn_beta = (const float*)d_in[6];
    const float* w1 = (const float*)d_in[7];
    const float* g1 = (const float*)d_in[8];
    const float* b1 = (const float*)d_in[9];
    const float* w2 = (const float*)d_in[10];
    const float* g2 = (const float*)d_in[11];
    const float* b2 = (const float*)d_in[12];
    const float* w3 = (const float*)d_in[13];
    const float* b3 = (const float*)d_in[14];
    const int* x = (const int*)d_in[15];
    const int* edge_index = (const int*)d_in[16];
    const int* batch = (const int*)d_in[17];
    float* out = (float*)d_out;

    const int N = in_sizes[15] / 9;
    const int E = in_sizes[16] / 2;
    const int G = NGRAPH;
    const int NCHUNK = (N + 1023) / 1024;  // scan chunks

    // workspace carve
    char* p = (char*)d_ws;
    auto alloc = [&](size_t bytes) -> void* {
        void* r = (void*)p;
        p += (bytes + 255) & ~(size_t)255;
        return r;
    };
    float* h = (float*)alloc((size_t)N * 256 * 4);
    short* hb = (short*)alloc((size_t)N * 256 * 2);
    float* outb = (float*)alloc((size_t)N * 256 * 4);
    short* bases = (short*)alloc((size_t)N * 128 * 2);
    float* wts = (float*)alloc((size_t)N * 96 * 4);
    short* WT = (short*)alloc((size_t)4 * 224 * 256 * 2);
    int* row_ptr = (int*)alloc((size_t)(N + 1) * 4);
    int* cnt = (int*)alloc((size_t)N * 4);
    int* woff = (int*)alloc((size_t)N * 4);
    int* blksum = (int*)alloc((size_t)256 * 4);
    int* srcs = (int*)alloc((size_t)(E + N) * 4);
    float* partial = (float*)alloc((size_t)SNB * 2 * 256 * 4);
    float* ss = (float*)alloc((size_t)2 * 256 * 4);
    float* g = (float*)alloc((size_t)G * 256 * 4);
    float* z1 = (float*)alloc((size_t)G * 128 * 4);
    float* z2 = (float*)alloc((size_t)G * 64 * 4);

    // atom encoder + weight prep
    atom_enc<<<N, 256, 0, stream>>>(x, atom_emb, h, hb, N);
    prep_wt<<<4 * 224, 256, 0, stream>>>(bases_W, comb_W, WT);

    // CSR build
    init_cnt<<<(N + 255) / 256, 256, 0, stream>>>(cnt, N);
    csr_count<<<(E + 255) / 256, 256, 0, stream>>>(edge_index, E, cnt);
    scan_s1<<<NCHUNK, 256, 0, stream>>>(cnt, blksum, N);
    scan_s2<<<1, 256, 0, stream>>>(blksum, NCHUNK, row_ptr, N);
    scan_s3<<<NCHUNK, 256, 0, stream>>>(cnt, blksum, row_ptr, woff, N);
    csr_scatter<<<(E + N + 1023) / 1024, 256, 0, stream>>>(edge_index, E, N, woff, srcs);

    for (int l = 0; l < 4; ++l) {
        const short* WTl = WT + (size_t)l * 224 * 256;
        const float* cb = comb_b + (size_t)l * 96;
        const float* cbias = conv_bias + (size_t)l * 256;
        const float* gam = bn_gamma + (size_t)l * 256;
        const float* bet = bn_beta + (size_t)l * 256;

        gemm_mfma<<<(N + 63) / 64, 256, 0, stream>>>(hb, WTl, cb, bases, wts, N);
        agg_einsum<<<(N + 3) / 4, 256, 0, stream>>>(bases, wts, row_ptr, srcs, cbias, outb, N);
        bn_stats256<<<SNB, 256, 0, stream>>>((const float4*)outb, N, partial);
        bn_finalize<<<256, 256, 0, stream>>>(partial, SNB, 256, N, gam, bet, ss);
        int total4 = N * 256 / 4;
        bn_apply_res4<<<(total4 + 255) / 256, 256, 0, stream>>>((float4*)h, (const float4*)outb, ss, hb, total4);
    }

    // pool
    pool_kernel<<<G, 256, 0, stream>>>(h, batch, N, g);

    // MLP layer 1: 256 -> 128
    mlp_gemm<<<G, 128, 256 * 4, stream>>>(g, w1, z1, 256, 128);
    bn_stats<<<64, 128, 0, stream>>>(z1, G, 128, partial);
    bn_finalize<<<128, 256, 0, stream>>>(partial, 64, 128, G, g1, b1, ss);
    bn_apply<<<(G * 128 + 255) / 256, 256, 0, stream>>>(z1, ss, G * 128, 128, 127);

    // MLP layer 2: 128 -> 64
    mlp_gemm<<<G, 64, 128 * 4, stream>>>(z1, w2, z2, 128, 64);
    bn_stats<<<64, 64, 0, stream>>>(z2, G, 64, partial);
    bn_finalize<<<64, 256, 0, stream>>>(partial, 64, 64, G, g2, b2, ss);
    bn_apply<<<(G * 64 + 255) / 256, 256, 0, stream>>>(z2, ss, G * 64, 64, 63);

    // final: 64 -> 1
    final_gemm<<<(G + 255) / 256, 256, 0, stream>>>(z2, w3, b3, out, G);
}